// Round 9
// baseline (808.737 us; speedup 1.0000x reference)
//
#include <hip/hip_runtime.h>
#include <stdint.h>

#define N_PTS 240000
#define NV    11059200      // 2*480*360*32 voxels
#define NWORDS 172800       // NV/64 bitmap words
#define NBLK  938           // build grid; 938*256 = 240128 >= N_PTS
#define NB_WORD 675         // NWORDS/256 (exact)
#define NBLK_MLP 3750       // N_PTS/64
#define PA 264              // LDS row pitch (shorts)

typedef __bf16 bf16x8 __attribute__((ext_vector_type(8)));
typedef short  short8 __attribute__((ext_vector_type(8)));
typedef float  f32x4  __attribute__((ext_vector_type(4)));

__device__ __forceinline__ unsigned short f2bf(float f) {
  unsigned u = __builtin_bit_cast(unsigned, f);
  return (unsigned short)((u + 0x7FFFu + ((u >> 16) & 1u)) >> 16);   // RNE
}
__device__ __forceinline__ float bf2f(unsigned short h) {
  unsigned u = ((unsigned)h) << 16;
  return __builtin_bit_cast(float, u);
}

// ---- software grid barrier: all NBLK blocks co-resident (launch_bounds(256,4) -> >=4 blk/CU,
// 1024 >= 938). One release add + RELAXED spin (s_sleep) + one acquire RMW per block:
// no per-poll cache invalidates (the r6-r8 lookback regression).
__device__ __forceinline__ void gbar(unsigned* bar, unsigned goal) {
  __syncthreads();
  if (threadIdx.x == 0) {
    __hip_atomic_fetch_add(bar, 1u, __ATOMIC_RELEASE, __HIP_MEMORY_SCOPE_AGENT);
    while (__hip_atomic_load(bar, __ATOMIC_RELAXED, __HIP_MEMORY_SCOPE_AGENT) < goal)
      __builtin_amdgcn_s_sleep(16);
    (void)__hip_atomic_fetch_add(bar, 0u, __ATOMIC_ACQUIRE, __HIP_MEMORY_SCOPE_AGENT);
  }
  __syncthreads();
}

__device__ __forceinline__ unsigned block_sum(unsigned v, unsigned* s4, int t) {
  #pragma unroll
  for (int o = 32; o; o >>= 1) v += __shfl_down(v, o);
  if ((t & 63) == 0) s4[t >> 6] = v;
  __syncthreads();
  unsigned r = s4[0] + s4[1] + s4[2] + s4[3];
  __syncthreads();
  return r;
}

// ---------------- fused build: prep + vox + unique + CSR + labels (6 grid barriers) ----
__global__ __launch_bounds__(256, 4) void build_kernel(
    const float* __restrict__ bng0, const float* __restrict__ bnb0, const float* __restrict__ bnm0, const float* __restrict__ bnv0,
    const float* __restrict__ bng1, const float* __restrict__ bnb1, const float* __restrict__ bnm1, const float* __restrict__ bnv1,
    const float* __restrict__ bng2, const float* __restrict__ bnb2, const float* __restrict__ bnm2, const float* __restrict__ bnv2,
    const float* __restrict__ bng3, const float* __restrict__ bnb3, const float* __restrict__ bnm3, const float* __restrict__ bnv3,
    const float* __restrict__ w1, const float* __restrict__ b1,
    const float* __restrict__ w2, const float* __restrict__ b2,
    const float* __restrict__ w3, const float* __restrict__ b3,
    const float* __restrict__ w4, const float* __restrict__ wc,
    float* __restrict__ s0, float* __restrict__ t0, float* __restrict__ w1e, float* __restrict__ be1,
    float* __restrict__ be2, float* __restrict__ be3,
    unsigned short* __restrict__ w2t, unsigned short* __restrict__ w3t, unsigned short* __restrict__ w4t,
    unsigned short* __restrict__ wct,
    const float* __restrict__ xyz, const int* __restrict__ bidx, const int* __restrict__ ptlab,
    unsigned long long* __restrict__ bitmap, unsigned* __restrict__ bsumA, unsigned* __restrict__ bsumB,
    unsigned* __restrict__ wordpref, unsigned* __restrict__ unqvals,
    unsigned* __restrict__ unq_inv, unsigned* __restrict__ cnt, unsigned* __restrict__ counts,
    unsigned* __restrict__ offv, unsigned* __restrict__ cur, unsigned* __restrict__ plist,
    const float* __restrict__ bc,
    float* __restrict__ out_cat, float* __restrict__ out_unq, float* __restrict__ out_lab,
    float* __restrict__ out_pooled, unsigned* __restrict__ bars)
{
  __shared__ unsigned sh[256];
  __shared__ unsigned s4[4];
  const int t = threadIdx.x, b = blockIdx.x;
  const int gid = b * 256 + t;
  unsigned flat = 0;                                 // live V -> I
  unsigned rseg = 0;                                 // live I -> P

  // ======== phase V: weight prep + voxelize + zero out_lab ========
  if (gid < 65536) {
    const int id = gid;
    { int c = id >> 8, k = id & 255; w4t[c * 256 + k] = f2bf(w4[k * 256 + c]); }
    if (id < 32768) { int c = id >> 7, k = id & 127;
      float s = bng3[c] * rsqrtf(bnv3[c] + 1e-5f);
      w3t[c * 128 + k] = f2bf(w3[k * 256 + c] * s); }
    if (id < 8192) { int c = id >> 6, k = id & 63;
      float s = bng2[c] * rsqrtf(bnv2[c] + 1e-5f);
      w2t[c * 64 + k] = f2bf(w2[k * 128 + c] * s); }
    if (id < 4096) { int c = id >> 8, k = id & 255;
      wct[c * 256 + k] = f2bf(wc[k * 16 + c]); }     // wc transposed [16][256]
    if (id < 576) { int k = id / 64, c = id % 64;
      float s = bng1[c] * rsqrtf(bnv1[c] + 1e-5f);
      w1e[k * 64 + c] = w1[k * 64 + c] * s; }
    if (id < 64)  { float s = bng1[id] * rsqrtf(bnv1[id] + 1e-5f); be1[id] = (b1[id] - bnm1[id]) * s + bnb1[id]; }
    if (id < 128) { float s = bng2[id] * rsqrtf(bnv2[id] + 1e-5f); be2[id] = (b2[id] - bnm2[id]) * s + bnb2[id]; }
    if (id < 256) { float s = bng3[id] * rsqrtf(bnv3[id] + 1e-5f); be3[id] = (b3[id] - bnm3[id]) * s + bnb3[id]; }
    if (id < 9)   { float s = bng0[id] * rsqrtf(bnv0[id] + 1e-5f); s0[id] = s; t0[id] = bnb0[id] - bnm0[id] * s; }
  }
  if (gid < N_PTS) {
    const int j = gid;
    out_unq[j] = -1.0f;                               // jnp.unique fill_value
    const float PI_F = 3.14159265358979323846f;       // == float32(np.pi)
    const float minb[3] = {0.0f, -PI_F, -4.0f};
    const float maxb[3] = {50.0f, PI_F, 2.0f};
    const float gm1[3]  = {479.0f, 359.0f, 31.0f};
    int ind[3];
    #pragma unroll
    for (int d = 0; d < 3; ++d) {
      float itv = (maxb[d] - minb[d]) / gm1[d];       // IEEE fp32 div (no fast-math)
      float x  = xyz[(size_t)j * 3 + d];
      float cl = fminf(fmaxf(x, minb[d]), maxb[d]);
      ind[d] = (int)floorf((cl - minb[d]) / itv);
    }
    const int bi = bidx[j];
    flat = ((unsigned)(bi * 480 + ind[0]) * 360u + (unsigned)ind[1]) * 32u + (unsigned)ind[2];
    atomicOr(&bitmap[flat >> 6], 1ull << (flat & 63u));
    float* oc = out_cat + (size_t)j * 4;
    oc[0] = (float)bi; oc[1] = (float)ind[0]; oc[2] = (float)ind[1]; oc[3] = (float)ind[2];
  }
  for (unsigned i = (unsigned)gid; i < NV / 4; i += NBLK * 256)       // zero labels output (44 MB)
    *(f32x4*)&out_lab[(size_t)i * 4] = (f32x4){0.f, 0.f, 0.f, 0.f};
  gbar(&bars[0], NBLK);

  // ======== phase U1: per-block popcount totals ========
  unsigned long long word = 0; unsigned uown = 0, ulocal = 0;
  if (b < NB_WORD) {
    word = bitmap[b * 256 + t];
    uown = (unsigned)__popcll(word);
    sh[t] = uown; __syncthreads();
    for (int off = 1; off < 256; off <<= 1) {
      unsigned v = (t >= off) ? sh[t - off] : 0u;
      __syncthreads(); sh[t] += v; __syncthreads();
    }
    ulocal = sh[t] - uown;
    if (t == 0) bsumA[b] = sh[255];
  }
  gbar(&bars[1], NBLK);

  // ======== phase U2: exclusive prefix (brute-force over L2-hot totals) + unq scatter ========
  if (b < NB_WORD) {
    unsigned v = 0;
    for (int i = t; i < b; i += 256) v += bsumA[i];
    unsigned excl = block_sum(v, s4, t);
    unsigned r = excl + ulocal;
    wordpref[b * 256 + t] = r;
    unsigned long long wtmp = word;
    while (wtmp) {
      int bit = __builtin_ctzll(wtmp);
      unsigned id = (unsigned)(b * 256 + t) * 64u + (unsigned)bit;
      unqvals[r] = id;
      out_unq[r] = (float)id;                         // exact: id < 2^24
      ++r;
      wtmp &= wtmp - 1;
    }
  }
  gbar(&bars[2], NBLK);

  // ======== phase I: inverse rank + segment sizes + packed label histogram ========
  if (gid < N_PTS) {
    const unsigned w = flat >> 6, bb = flat & 63u;
    rseg = wordpref[w] + (unsigned)__popcll(bitmap[w] & ((1ull << bb) - 1ull));
    unq_inv[gid] = rseg;
    atomicAdd(&cnt[rseg], 1u);
    const unsigned lab = (unsigned)ptlab[gid];
    atomicAdd(&counts[(size_t)rseg * 10 + (lab >> 1)], 1u << ((lab & 1u) * 16));  // 2x16-bit packed
  }
  gbar(&bars[3], NBLK);

  // ======== phase C1: per-block cnt totals ========
  unsigned cown = (gid < N_PTS) ? cnt[gid] : 0u, clocal = 0;
  {
    sh[t] = cown; __syncthreads();
    for (int off = 1; off < 256; off <<= 1) {
      unsigned v = (t >= off) ? sh[t - off] : 0u;
      __syncthreads(); sh[t] += v; __syncthreads();
    }
    clocal = sh[t] - cown;
    if (t == 0) bsumB[b] = sh[255];
  }
  gbar(&bars[4], NBLK);

  // ======== phase C2: CSR offsets ========
  {
    unsigned v = 0;
    for (int i = t; i < b; i += 256) v += bsumB[i];
    unsigned excl = block_sum(v, s4, t);
    if (gid < N_PTS) { unsigned e = excl + clocal; offv[gid] = e; cur[gid] = e; }
  }
  gbar(&bars[5], NBLK);

  // ======== phase P: plist scatter + label argmax + empty-segment pooled fill ========
  if (gid < N_PTS) {
    plist[atomicAdd(&cur[rseg], 1u)] = (unsigned)gid;
    const int u = gid;
    if (cnt[u] == 0) {
      #pragma unroll
      for (int c = 0; c < 16; ++c) out_pooled[(size_t)u * 16 + c] = fmaxf(bc[c], 0.f);
    } else {
      const unsigned* c = counts + (size_t)u * 10;
      int best = 0; unsigned bv = c[0] & 0xFFFFu;
      #pragma unroll
      for (int l = 1; l < 20; ++l) {
        unsigned v = (c[l >> 1] >> ((l & 1) * 16)) & 0xFFFFu;
        if (v > bv) { bv = v; best = l; }
      }
      out_lab[unqvals[u]] = (float)best;
    }
  }
}

// ---- block-wide GEMM stage, column-strip waves, SWAPPED-D epilogue (b64 LDS writes) ----
// mfma(w_frag, x_frag): D row'=quad*4+r = OUT COLUMN, D col=l15 = OUT ROW (within mt tile).
// All k-loop LDS reads precede the (optional) mid barrier -> in-place/overlapping out is safe.
template<int K, int C, bool RELU, bool MIDB>
__device__ __forceinline__ void gemm_stage(
    const unsigned short* __restrict__ Wt,     // [C][K] bf16, global (L2-hot)
    const float* __restrict__ bias,            // [C]
    const unsigned short* in,                  // LDS, pitch PA (col-offset base)
    unsigned short* outp,                      // LDS, pitch PA (may overlap in)
    int wave, int l15, int quad)
{
  constexpr int KC = K / 32;
  constexpr int NT = C / 64;                   // 16-col tiles per wave (weights read ONCE/block)
  f32x4 acc[4][NT];
  #pragma unroll
  for (int mt = 0; mt < 4; ++mt)
    #pragma unroll
    for (int nt = 0; nt < NT; ++nt) acc[mt][nt] = (f32x4){0.f, 0.f, 0.f, 0.f};
  const unsigned short* wp[NT];
  #pragma unroll
  for (int nt = 0; nt < NT; ++nt)
    wp[nt] = Wt + (size_t)(wave * 16 * NT + nt * 16 + l15) * K + quad * 8;
  #pragma unroll
  for (int kc = 0; kc < KC; ++kc) {
    bf16x8 b[NT];
    #pragma unroll
    for (int nt = 0; nt < NT; ++nt)
      b[nt] = __builtin_bit_cast(bf16x8, *(const short8*)(wp[nt] + kc * 32));
    #pragma unroll
    for (int mt = 0; mt < 4; ++mt) {
      bf16x8 a = __builtin_bit_cast(bf16x8, *(const short8*)&in[(mt * 16 + l15) * PA + kc * 32 + quad * 8]);
      #pragma unroll
      for (int nt = 0; nt < NT; ++nt)
        acc[mt][nt] = __builtin_amdgcn_mfma_f32_16x16x32_bf16(b[nt], a, acc[mt][nt], 0, 0, 0);
    }
  }
  if (MIDB) __syncthreads();                   // reads drained before overlapping writes
  #pragma unroll
  for (int mt = 0; mt < 4; ++mt)
    #pragma unroll
    for (int nt = 0; nt < NT; ++nt) {
      const int cbase = wave * 16 * NT + nt * 16 + quad * 4;
      const f32x4 bs = *(const f32x4*)&bias[cbase];
      unsigned short h[4];
      #pragma unroll
      for (int r = 0; r < 4; ++r) {
        float y = acc[mt][nt][r] + bs[r];
        if (RELU) y = fmaxf(y, 0.f);
        h[r] = f2bf(y);
      }
      uint2 pk; pk.x = (unsigned)h[0] | ((unsigned)h[1] << 16);
      pk.y = (unsigned)h[2] | ((unsigned)h[3] << 16);
      *(uint2*)&outp[(mt * 16 + l15) * PA + cbase] = pk;   // ds_write_b64
    }
  __syncthreads();
}

// ---------------- fused MLP + sparse segment-max fixup + compression (as r8) ----------------
__global__ __launch_bounds__(256, 4) void mlp_pool_kernel(
    const float* __restrict__ ptfea, const float* __restrict__ xyz, const int* __restrict__ shuf,
    const unsigned* __restrict__ plist, const unsigned* __restrict__ unq_inv,
    const unsigned* __restrict__ offv, const unsigned* __restrict__ cnt,
    const float* __restrict__ s0, const float* __restrict__ t0,
    const float* __restrict__ w1e, const float* __restrict__ be1,
    const unsigned short* __restrict__ w2t, const float* __restrict__ be2,
    const unsigned short* __restrict__ w3t, const float* __restrict__ be3,
    const unsigned short* __restrict__ w4t, const float* __restrict__ b4,
    const unsigned short* __restrict__ wct, const float* __restrict__ bc,
    unsigned short* __restrict__ partials, float* __restrict__ out_pooled)
{
  __shared__ __align__(16) unsigned short buf[64 * PA];
  __shared__ int segs[64];
  __shared__ int jrows[64];
  __shared__ int s_alast;
  __shared__ int s_nrun;
  __shared__ unsigned short s_runs[32];              // (r<<8)|e for runs with len>1
  __shared__ unsigned char s_lead[64], s_comp[64];
  const int tid  = threadIdx.x;
  const int wave = tid >> 6, lane = tid & 63;
  const int l15 = lane & 15, quad = lane >> 4;
  const int row0 = blockIdx.x * 64;

  if (tid == 0) { s_alast = 0; s_nrun = 0; }
  if (lane < 16) {                                   // wave-local write; same-wave read below
    const int r = wave * 16 + lane;
    int j = (int)plist[row0 + r];
    jrows[r] = j;
    segs[r] = (int)unq_inv[j];
  }

  // ---- stage 0: features + bn0 + layer1 (scalar fp32); 4 lanes/row, wave-local rows ----
  {
    const int r = wave * 16 + (lane >> 2), part = lane & 3;
    const int sj = shuf[jrows[r]];
    const float PI_F = 3.14159265358979323846f;
    const float minb[3] = {0.0f, -PI_F, -4.0f};
    const float maxb[3] = {50.0f, PI_F, 2.0f};
    const float gm1[3]  = {479.0f, 359.0f, 31.0f};
    float x0[9];
    #pragma unroll
    for (int d = 0; d < 3; ++d) {
      float itv = (maxb[d] - minb[d]) / gm1[d];
      float x   = xyz[(size_t)sj * 3 + d];
      float cl  = fminf(fmaxf(x, minb[d]), maxb[d]);
      float fi  = floorf((cl - minb[d]) / itv);
      float center = (fi + 0.5f) * itv + minb[d];
      x0[d] = (x - center) * s0[d] + t0[d];           // bn0 folded
    }
    #pragma unroll
    for (int d = 0; d < 6; ++d) x0[3 + d] = ptfea[(size_t)sj * 6 + d] * s0[3 + d] + t0[3 + d];
    unsigned short h[16];
    #pragma unroll
    for (int ci = 0; ci < 16; ++ci) {
      float acc = be1[part * 16 + ci];
      #pragma unroll
      for (int k = 0; k < 9; ++k) acc += x0[k] * w1e[k * 64 + part * 16 + ci];
      h[ci] = f2bf(fmaxf(acc, 0.0f));
    }
    *(short8*)&buf[r * PA + part * 16]     = *(short8*)&h[0];
    *(short8*)&buf[r * PA + part * 16 + 8] = *(short8*)&h[8];
  }
  __syncthreads();

  // ---- L2 [64->128] cols 0->136 (disjoint: no mid barrier); L3 [128->256] 136->0; L4 in-place ----
  gemm_stage< 64, 128, true,  false>(w2t, be2, buf,       buf + 136, wave, l15, quad);
  gemm_stage<128, 256, true,  true >(w3t, be3, buf + 136, buf,       wave, l15, quad);
  gemm_stage<256, 256, false, true >(w4t, b4,  buf,       buf,       wave, l15, quad);

  // ---- wave 0: run analysis + compact multi-run list ----
  if (tid < 64) {
    const int r = tid;
    bool lead = (r == 0) || (segs[r] != segs[r - 1]);
    s_lead[r] = lead ? 1 : 0;
    unsigned char comp = 0;
    int e = r + 1;
    if (lead) {
      atomicMax(&s_alast, r);
      while (e < 64 && segs[e] == segs[r]) ++e;
      const unsigned s = (unsigned)segs[r];
      comp = (offv[s] == (unsigned)(row0 + r) && offv[s] + cnt[s] == (unsigned)(row0 + e)) ? 1 : 0;
    }
    s_comp[r] = comp;
    const bool multi = lead && (e - r) > 1;
    unsigned long long mm = __ballot(multi);
    if (multi) {
      int idx = (int)__popcll(mm & ((1ull << r) - 1ull));
      s_runs[idx] = (unsigned short)((r << 8) | e);
    }
    if (tid == 0) s_nrun = (int)__popcll(mm);
  }
  __syncthreads();

  // ---- sparse fixup: per multi-run, column-thread computes run max into the leader row ----
  {
    const int n = s_nrun;
    for (int i = 0; i < n; ++i) {
      const int re = s_runs[i];
      const int r = re >> 8, e = re & 255;
      float m = bf2f(buf[r * PA + tid]);
      for (int rr = r + 1; rr < e; ++rr) m = fmaxf(m, bf2f(buf[rr * PA + tid]));
      buf[r * PA + tid] = f2bf(m);
    }
  }
  __syncthreads();

  // ---- boundary partials (first/last incomplete runs; rows 0 and alast are leaders) ----
  {
    const int c = tid;
    const int alast = s_alast;
    const size_t b2 = (size_t)blockIdx.x * 2;
    if (!s_comp[0])     partials[b2 * 256 + c]       = buf[0 * PA + c];
    if (!s_comp[alast]) partials[(b2 + 1) * 256 + c] = buf[alast * PA + c];
  }

  // ---- compression: pooled[rows wave*16+l15, 256] @ wct^T; swapped-D -> float4 stores ----
  {
    const unsigned short* wp = wct + l15 * 256 + quad * 8;
    f32x4 acc = (f32x4){0.f, 0.f, 0.f, 0.f};
    #pragma unroll
    for (int kc = 0; kc < 256; kc += 32) {
      bf16x8 w = __builtin_bit_cast(bf16x8, *(const short8*)(wp + kc));
      bf16x8 x = __builtin_bit_cast(bf16x8, *(const short8*)&buf[(wave * 16 + l15) * PA + kc + quad * 8]);
      acc = __builtin_amdgcn_mfma_f32_16x16x32_bf16(w, x, acc, 0, 0, 0);
    }
    const int r1 = wave * 16 + l15;                  // pooled row (D col = l15)
    if (s_lead[r1] && s_comp[r1]) {
      const f32x4 bcv = *(const f32x4*)&bc[quad * 4];
      f32x4 v;
      #pragma unroll
      for (int r = 0; r < 4; ++r) v[r] = fmaxf(acc[r] + bcv[r], 0.f);   // cols quad*4+r
      *(f32x4*)&out_pooled[(size_t)segs[r1] * 16 + quad * 4] = v;
    }
  }
}

// ---------------- merge block-spanning segments from partials ----
__global__ __launch_bounds__(256) void merge_kernel(
    const unsigned* __restrict__ plist, const unsigned* __restrict__ unq_inv,
    const unsigned* __restrict__ offv, const unsigned* __restrict__ cnt,
    const unsigned short* __restrict__ partials,
    const float* __restrict__ wc, const float* __restrict__ bc,
    float* __restrict__ out_pooled)
{
  __shared__ float pooled[256];
  __shared__ float psum[256];
  const int b = blockIdx.x;
  const unsigned s = unq_inv[plist[(size_t)b * 64 + 63]];
  const unsigned o = offv[s], e = o + cnt[s];
  if ((o >> 6) != (unsigned)b) return;              // owner = block where segment starts
  if (e <= (unsigned)(b + 1) * 64) return;          // doesn't span a boundary
  const int B1 = (int)((e - 1) >> 6);
  const int c = threadIdx.x;
  float m = bf2f(partials[((size_t)2 * b + 1) * 256 + c]);    // head partial (last run of b)
  for (int bb = b + 1; bb <= B1; ++bb)
    m = fmaxf(m, bf2f(partials[(size_t)2 * bb * 256 + c]));   // tails (first run of bb)
  pooled[c] = m;
  __syncthreads();
  const int co = c & 15, kg = c >> 4;
  float p = 0.f;
  #pragma unroll
  for (int k = kg * 16; k < kg * 16 + 16; ++k) p += pooled[k] * wc[k * 16 + co];
  psum[c] = p;
  __syncthreads();
  if (c < 16) {
    float acc = bc[c];
    #pragma unroll
    for (int g = 0; g < 16; ++g) acc += psum[g * 16 + c];
    out_pooled[(size_t)s * 16 + c] = fmaxf(acc, 0.f);
  }
}

extern "C" void kernel_launch(void* const* d_in, const int* in_sizes, int n_in,
                              void* d_out, int out_size, void* d_ws, size_t ws_size,
                              hipStream_t stream)
{
  const float* pt_fea = (const float*)d_in[0];
  const float* xyz    = (const float*)d_in[1];
  const int*   bidx   = (const int*)d_in[2];
  const int*   ptlab  = (const int*)d_in[3];
  const int*   shuf   = (const int*)d_in[4];
  const float* bng0 = (const float*)d_in[5],  *bnb0 = (const float*)d_in[6],  *bnm0 = (const float*)d_in[7],  *bnv0 = (const float*)d_in[8];
  const float* bng1 = (const float*)d_in[9],  *bnb1 = (const float*)d_in[10], *bnm1 = (const float*)d_in[11], *bnv1 = (const float*)d_in[12];
  const float* bng2 = (const float*)d_in[13], *bnb2 = (const float*)d_in[14], *bnm2 = (const float*)d_in[15], *bnv2 = (const float*)d_in[16];
  const float* bng3 = (const float*)d_in[17], *bnb3 = (const float*)d_in[18], *bnm3 = (const float*)d_in[19], *bnv3 = (const float*)d_in[20];
  const float* w1 = (const float*)d_in[21], *b1 = (const float*)d_in[22];
  const float* w2 = (const float*)d_in[23], *b2 = (const float*)d_in[24];
  const float* w3 = (const float*)d_in[25], *b3 = (const float*)d_in[26];
  const float* w4 = (const float*)d_in[27], *b4 = (const float*)d_in[28];
  const float* wc = (const float*)d_in[29], *bc = (const float*)d_in[30];

  float* out        = (float*)d_out;                // outputs int64/f32/int32 -> float32 buffer
  float* out_unq    = out;                          // [240000]
  float* out_pooled = out + 240000;                 // [240000,16]
  float* out_lab    = out + 4080000;                // [2,480,360,32]
  float* out_cat    = out + 15139200;               // [240000,4]

  char* wsb = (char*)d_ws;
  size_t o = 0;
  auto alloc = [&](size_t bytes) -> void* { void* p = wsb + o; o = (o + bytes + 255) & ~(size_t)255; return p; };
  // zero-init region (single memset): bitmap | cnt | counts | barrier counters
  unsigned long long* bitmap = (unsigned long long*)alloc((size_t)NWORDS * 8);
  unsigned* cnt    = (unsigned*)alloc((size_t)N_PTS * 4);
  unsigned* counts = (unsigned*)alloc((size_t)N_PTS * 10 * 4);
  unsigned* bars   = (unsigned*)alloc(8 * 4);
  const size_t zero_bytes = o;
  float* s0  = (float*)alloc(9 * 4);
  float* t0  = (float*)alloc(9 * 4);
  float* w1e = (float*)alloc(576 * 4);
  float* be1 = (float*)alloc(64 * 4);
  float* be2 = (float*)alloc(128 * 4);
  float* be3 = (float*)alloc(256 * 4);
  unsigned short* w2t = (unsigned short*)alloc(8192 * 2);
  unsigned short* w3t = (unsigned short*)alloc(32768 * 2);
  unsigned short* w4t = (unsigned short*)alloc(65536 * 2);
  unsigned short* wct = (unsigned short*)alloc(4096 * 2);
  unsigned* unq_inv  = (unsigned*)alloc((size_t)N_PTS * 4);
  unsigned* unqvals  = (unsigned*)alloc((size_t)N_PTS * 4);
  unsigned* offv     = (unsigned*)alloc((size_t)N_PTS * 4);
  unsigned* cur      = (unsigned*)alloc((size_t)N_PTS * 4);
  unsigned* plist    = (unsigned*)alloc((size_t)N_PTS * 4);
  unsigned* wordpref = (unsigned*)alloc((size_t)NWORDS * 4);
  unsigned* bsumA    = (unsigned*)alloc(NB_WORD * 4);
  unsigned* bsumB    = (unsigned*)alloc(NBLK * 4);
  unsigned short* partials = (unsigned short*)alloc((size_t)NBLK_MLP * 2 * 256 * 2);
  // total ~22 MB

  hipMemsetAsync(bitmap, 0, zero_bytes, stream);

  build_kernel<<<NBLK, 256, 0, stream>>>(
      bng0, bnb0, bnm0, bnv0, bng1, bnb1, bnm1, bnv1,
      bng2, bnb2, bnm2, bnv2, bng3, bnb3, bnm3, bnv3,
      w1, b1, w2, b2, w3, b3, w4, wc,
      s0, t0, w1e, be1, be2, be3, w2t, w3t, w4t, wct,
      xyz, bidx, ptlab,
      bitmap, bsumA, bsumB, wordpref, unqvals,
      unq_inv, cnt, counts, offv, cur, plist, bc,
      out_cat, out_unq, out_lab, out_pooled, bars);
  mlp_pool_kernel<<<NBLK_MLP, 256, 0, stream>>>(pt_fea, xyz, shuf, plist, unq_inv, offv, cnt,
                                                s0, t0, w1e, be1, w2t, be2, w3t, be3, w4t, b4,
                                                wct, bc, partials, out_pooled);
  merge_kernel<<<NBLK_MLP, 256, 0, stream>>>(plist, unq_inv, offv, cnt, partials, wc, bc, out_pooled);
}

// Round 10
// 369.517 us; speedup vs baseline: 2.1886x; 2.1886x over previous
//
#include <hip/hip_runtime.h>
#include <stdint.h>

#define N_PTS 240000
#define NV    11059200      // 2*480*360*32 voxels
#define NWORDS 172800       // NV/64 bitmap words
#define NB_PT 938           // ceil(N_PTS/256)
#define NB_WORD 675         // NWORDS/256 (exact)
#define NBLK_MLP 3750       // N_PTS/64
#define PA 264              // LDS row pitch (shorts)

typedef __bf16 bf16x8 __attribute__((ext_vector_type(8)));
typedef short  short8 __attribute__((ext_vector_type(8)));
typedef float  f32x4  __attribute__((ext_vector_type(4)));

__device__ __forceinline__ unsigned short f2bf(float f) {
  unsigned u = __builtin_bit_cast(unsigned, f);
  return (unsigned short)((u + 0x7FFFu + ((u >> 16) & 1u)) >> 16);   // RNE
}
__device__ __forceinline__ float bf2f(unsigned short h) {
  unsigned u = ((unsigned)h) << 16;
  return __builtin_bit_cast(float, u);
}

// ---------------- fused: weight prep (blocks 0..255) + per-point voxelize (blocks 256..1193) ----
__global__ void prep_vox_kernel(
    const float* __restrict__ bng0, const float* __restrict__ bnb0, const float* __restrict__ bnm0, const float* __restrict__ bnv0,
    const float* __restrict__ bng1, const float* __restrict__ bnb1, const float* __restrict__ bnm1, const float* __restrict__ bnv1,
    const float* __restrict__ bng2, const float* __restrict__ bnb2, const float* __restrict__ bnm2, const float* __restrict__ bnv2,
    const float* __restrict__ bng3, const float* __restrict__ bnb3, const float* __restrict__ bnm3, const float* __restrict__ bnv3,
    const float* __restrict__ w1, const float* __restrict__ b1,
    const float* __restrict__ w2, const float* __restrict__ b2,
    const float* __restrict__ w3, const float* __restrict__ b3,
    const float* __restrict__ w4, const float* __restrict__ wc,
    float* __restrict__ s0, float* __restrict__ t0, float* __restrict__ w1e, float* __restrict__ be1,
    float* __restrict__ be2, float* __restrict__ be3,
    unsigned short* __restrict__ w2t, unsigned short* __restrict__ w3t, unsigned short* __restrict__ w4t,
    unsigned short* __restrict__ wct,
    const float* __restrict__ xyz, const int* __restrict__ bidx,
    unsigned* __restrict__ flatkeys, unsigned long long* __restrict__ bitmap,
    float* __restrict__ out_cat, float* __restrict__ out_unq)
{
  if (blockIdx.x < 256) {
    const int id = blockIdx.x * 256 + threadIdx.x;   // covers 65536 exactly
    { int c = id >> 8, k = id & 255; w4t[c * 256 + k] = f2bf(w4[k * 256 + c]); }
    if (id < 32768) { int c = id >> 7, k = id & 127;
      float s = bng3[c] * rsqrtf(bnv3[c] + 1e-5f);
      w3t[c * 128 + k] = f2bf(w3[k * 256 + c] * s); }
    if (id < 8192) { int c = id >> 6, k = id & 63;
      float s = bng2[c] * rsqrtf(bnv2[c] + 1e-5f);
      w2t[c * 64 + k] = f2bf(w2[k * 128 + c] * s); }
    if (id < 4096) { int c = id >> 8, k = id & 255;
      wct[c * 256 + k] = f2bf(wc[k * 16 + c]); }     // wc transposed [16][256]
    if (id < 576) { int k = id / 64, c = id % 64;
      float s = bng1[c] * rsqrtf(bnv1[c] + 1e-5f);
      w1e[k * 64 + c] = w1[k * 64 + c] * s; }
    if (id < 64)  { float s = bng1[id] * rsqrtf(bnv1[id] + 1e-5f); be1[id] = (b1[id] - bnm1[id]) * s + bnb1[id]; }
    if (id < 128) { float s = bng2[id] * rsqrtf(bnv2[id] + 1e-5f); be2[id] = (b2[id] - bnm2[id]) * s + bnb2[id]; }
    if (id < 256) { float s = bng3[id] * rsqrtf(bnv3[id] + 1e-5f); be3[id] = (b3[id] - bnm3[id]) * s + bnb3[id]; }
    if (id < 9)   { float s = bng0[id] * rsqrtf(bnv0[id] + 1e-5f); s0[id] = s; t0[id] = bnb0[id] - bnm0[id] * s; }
    return;
  }
  const int j = (blockIdx.x - 256) * 256 + threadIdx.x;
  if (j >= N_PTS) return;
  out_unq[j] = -1.0f;                               // jnp.unique fill_value
  const float PI_F = 3.14159265358979323846f;       // == float32(np.pi)
  const float minb[3] = {0.0f, -PI_F, -4.0f};
  const float maxb[3] = {50.0f, PI_F, 2.0f};
  const float gm1[3]  = {479.0f, 359.0f, 31.0f};
  int ind[3];
  #pragma unroll
  for (int d = 0; d < 3; ++d) {
    float itv = (maxb[d] - minb[d]) / gm1[d];       // IEEE fp32 div (no fast-math)
    float x  = xyz[(size_t)j * 3 + d];
    float cl = fminf(fmaxf(x, minb[d]), maxb[d]);
    ind[d] = (int)floorf((cl - minb[d]) / itv);
  }
  const int bi = bidx[j];
  const unsigned flat = ((unsigned)(bi * 480 + ind[0]) * 360u + (unsigned)ind[1]) * 32u + (unsigned)ind[2];
  flatkeys[j] = flat;
  atomicOr(&bitmap[flat >> 6], 1ull << (flat & 63u));
  float* oc = out_cat + (size_t)j * 4;
  oc[0] = (float)bi; oc[1] = (float)ind[0]; oc[2] = (float)ind[1]; oc[3] = (float)ind[2];
}

// ---------------- bitmap popcount scan -> sorted unique ids + per-word prefix ----
__global__ void reduce_words(const unsigned long long* __restrict__ bm, unsigned* __restrict__ bsums) {
  __shared__ unsigned sh[256];
  const int w = blockIdx.x * 256 + threadIdx.x;     // exact coverage
  sh[threadIdx.x] = (unsigned)__popcll(bm[w]);
  __syncthreads();
  for (int s = 128; s > 0; s >>= 1) { if (threadIdx.x < s) sh[threadIdx.x] += sh[threadIdx.x + s]; __syncthreads(); }
  if (threadIdx.x == 0) bsums[blockIdx.x] = sh[0];
}

__global__ void scan_small(unsigned* __restrict__ d, int n) {   // one block, n <= 1024, in-place exclusive
  __shared__ unsigned sh[1024];
  const int t = threadIdx.x;
  unsigned own = (t < n) ? d[t] : 0u;
  sh[t] = own; __syncthreads();
  for (int off = 1; off < 1024; off <<= 1) {
    unsigned v = (t >= off) ? sh[t - off] : 0u;
    __syncthreads(); sh[t] += v; __syncthreads();
  }
  if (t < n) d[t] = sh[t] - own;
}

__global__ void scatter_unq(const unsigned long long* __restrict__ bm, const unsigned* __restrict__ bsums,
                            unsigned* __restrict__ wordpref, unsigned* __restrict__ unqvals,
                            float* __restrict__ out_unq) {
  __shared__ unsigned sh[256];
  const int t = threadIdx.x;
  const int w = blockIdx.x * 256 + t;
  unsigned long long word = bm[w];
  unsigned own = (unsigned)__popcll(word);
  sh[t] = own; __syncthreads();
  for (int off = 1; off < 256; off <<= 1) {
    unsigned v = (t >= off) ? sh[t - off] : 0u;
    __syncthreads(); sh[t] += v; __syncthreads();
  }
  unsigned r = bsums[blockIdx.x] + sh[t] - own;     // global exclusive prefix
  wordpref[w] = r;
  while (word) {
    int b = __builtin_ctzll(word);
    unsigned id = (unsigned)w * 64u + (unsigned)b;
    unqvals[r] = id;
    out_unq[r] = (float)id;                         // exact: id < 2^24
    ++r;
    word &= word - 1;
  }
}

// ---------------- inverse indices + segment sizes + packed label histogram ----
__global__ void inv_kernel(const unsigned* __restrict__ flatkeys, const unsigned long long* __restrict__ bm,
                           const unsigned* __restrict__ wordpref, const int* __restrict__ ptlab,
                           unsigned* __restrict__ unq_inv, unsigned* __restrict__ cnt, unsigned* __restrict__ counts) {
  const int j = blockIdx.x * 256 + threadIdx.x;
  if (j >= N_PTS) return;
  const unsigned f = flatkeys[j];
  const unsigned w = f >> 6, b = f & 63u;
  const unsigned r = wordpref[w] + (unsigned)__popcll(bm[w] & ((1ull << b) - 1ull));
  unq_inv[j] = r;
  atomicAdd(&cnt[r], 1u);
  const unsigned lab = (unsigned)ptlab[j];
  atomicAdd(&counts[(size_t)r * 10 + (lab >> 1)], 1u << ((lab & 1u) * 16));  // 2x16-bit packed
}

// ---------------- CSR build over segments ----
__global__ void reduce_cnt(const unsigned* __restrict__ cnt, unsigned* __restrict__ bsums) {
  __shared__ unsigned sh[256];
  const int j = blockIdx.x * 256 + threadIdx.x;
  sh[threadIdx.x] = (j < N_PTS) ? cnt[j] : 0u;
  __syncthreads();
  for (int s = 128; s > 0; s >>= 1) { if (threadIdx.x < s) sh[threadIdx.x] += sh[threadIdx.x + s]; __syncthreads(); }
  if (threadIdx.x == 0) bsums[blockIdx.x] = sh[0];
}
__global__ void scan_cnt(const unsigned* __restrict__ cnt, const unsigned* __restrict__ bsums,
                         unsigned* __restrict__ off, unsigned* __restrict__ cur) {
  __shared__ unsigned sh[256];
  const int t = threadIdx.x;
  const int j = blockIdx.x * 256 + t;
  unsigned own = (j < N_PTS) ? cnt[j] : 0u;
  sh[t] = own; __syncthreads();
  for (int o = 1; o < 256; o <<= 1) {
    unsigned v = (t >= o) ? sh[t - o] : 0u;
    __syncthreads(); sh[t] += v; __syncthreads();
  }
  if (j < N_PTS) { unsigned e = bsums[blockIdx.x] + sh[t] - own; off[j] = e; cur[j] = e; }
}

// ---------------- plist scatter + per-voxel label argmax + empty-segment pooled fill ----
__global__ void plist_labels_kernel(const unsigned* __restrict__ unq_inv, unsigned* __restrict__ cur,
                                    unsigned* __restrict__ plist,
                                    const unsigned* __restrict__ cnt, const unsigned* __restrict__ counts,
                                    const unsigned* __restrict__ unqvals, const float* __restrict__ bc,
                                    float* __restrict__ out_lab, float* __restrict__ out_pooled) {
  const int j = blockIdx.x * 256 + threadIdx.x;
  if (j >= N_PTS) return;
  plist[atomicAdd(&cur[unq_inv[j]], 1u)] = (unsigned)j;
  const int u = j;
  if (cnt[u] == 0) {
    #pragma unroll
    for (int c = 0; c < 16; ++c) out_pooled[(size_t)u * 16 + c] = fmaxf(bc[c], 0.f);
    return;
  }
  const unsigned* c = counts + (size_t)u * 10;
  int best = 0; unsigned bv = c[0] & 0xFFFFu;
  #pragma unroll
  for (int l = 1; l < 20; ++l) {
    unsigned v = (c[l >> 1] >> ((l & 1) * 16)) & 0xFFFFu;
    if (v > bv) { bv = v; best = l; }
  }
  out_lab[unqvals[u]] = (float)best;
}

// ---- block-wide GEMM stage, column-strip waves, SWAPPED-D epilogue (b64 LDS writes) ----
// mfma(w_frag, x_frag): D row'=quad*4+r = OUT COLUMN, D col=l15 = OUT ROW (within mt tile).
// All k-loop LDS reads precede the (optional) mid barrier -> in-place/overlapping out is safe.
template<int K, int C, bool RELU, bool MIDB>
__device__ __forceinline__ void gemm_stage(
    const unsigned short* __restrict__ Wt,     // [C][K] bf16, global (L2-hot)
    const float* __restrict__ bias,            // [C]
    const unsigned short* in,                  // LDS, pitch PA (col-offset base)
    unsigned short* outp,                      // LDS, pitch PA (may overlap in)
    int wave, int l15, int quad)
{
  constexpr int KC = K / 32;
  constexpr int NT = C / 64;                   // 16-col tiles per wave (weights read ONCE/block)
  f32x4 acc[4][NT];
  #pragma unroll
  for (int mt = 0; mt < 4; ++mt)
    #pragma unroll
    for (int nt = 0; nt < NT; ++nt) acc[mt][nt] = (f32x4){0.f, 0.f, 0.f, 0.f};
  const unsigned short* wp[NT];
  #pragma unroll
  for (int nt = 0; nt < NT; ++nt)
    wp[nt] = Wt + (size_t)(wave * 16 * NT + nt * 16 + l15) * K + quad * 8;
  #pragma unroll
  for (int kc = 0; kc < KC; ++kc) {
    bf16x8 b[NT];
    #pragma unroll
    for (int nt = 0; nt < NT; ++nt)
      b[nt] = __builtin_bit_cast(bf16x8, *(const short8*)(wp[nt] + kc * 32));
    #pragma unroll
    for (int mt = 0; mt < 4; ++mt) {
      bf16x8 a = __builtin_bit_cast(bf16x8, *(const short8*)&in[(mt * 16 + l15) * PA + kc * 32 + quad * 8]);
      #pragma unroll
      for (int nt = 0; nt < NT; ++nt)
        acc[mt][nt] = __builtin_amdgcn_mfma_f32_16x16x32_bf16(b[nt], a, acc[mt][nt], 0, 0, 0);
    }
  }
  if (MIDB) __syncthreads();                   // reads drained before overlapping writes
  #pragma unroll
  for (int mt = 0; mt < 4; ++mt)
    #pragma unroll
    for (int nt = 0; nt < NT; ++nt) {
      const int cbase = wave * 16 * NT + nt * 16 + quad * 4;
      const f32x4 bs = *(const f32x4*)&bias[cbase];
      unsigned short h[4];
      #pragma unroll
      for (int r = 0; r < 4; ++r) {
        float y = acc[mt][nt][r] + bs[r];
        if (RELU) y = fmaxf(y, 0.f);
        h[r] = f2bf(y);
      }
      uint2 pk; pk.x = (unsigned)h[0] | ((unsigned)h[1] << 16);
      pk.y = (unsigned)h[2] | ((unsigned)h[3] << 16);
      *(uint2*)&outp[(mt * 16 + l15) * PA + cbase] = pk;   // ds_write_b64
    }
  __syncthreads();
}

// ---------------- fused MLP + sparse segment-max fixup + compression (r8, best measured) ----
__global__ __launch_bounds__(256, 4) void mlp_pool_kernel(
    const float* __restrict__ ptfea, const float* __restrict__ xyz, const int* __restrict__ shuf,
    const unsigned* __restrict__ plist, const unsigned* __restrict__ unq_inv,
    const unsigned* __restrict__ offv, const unsigned* __restrict__ cnt,
    const float* __restrict__ s0, const float* __restrict__ t0,
    const float* __restrict__ w1e, const float* __restrict__ be1,
    const unsigned short* __restrict__ w2t, const float* __restrict__ be2,
    const unsigned short* __restrict__ w3t, const float* __restrict__ be3,
    const unsigned short* __restrict__ w4t, const float* __restrict__ b4,
    const unsigned short* __restrict__ wct, const float* __restrict__ bc,
    unsigned short* __restrict__ partials, float* __restrict__ out_pooled)
{
  __shared__ __align__(16) unsigned short buf[64 * PA];
  __shared__ int segs[64];
  __shared__ int jrows[64];
  __shared__ int s_alast;
  __shared__ int s_nrun;
  __shared__ unsigned short s_runs[32];              // (r<<8)|e for runs with len>1
  __shared__ unsigned char s_lead[64], s_comp[64];
  const int tid  = threadIdx.x;
  const int wave = tid >> 6, lane = tid & 63;
  const int l15 = lane & 15, quad = lane >> 4;
  const int row0 = blockIdx.x * 64;

  if (tid == 0) { s_alast = 0; s_nrun = 0; }
  if (lane < 16) {                                   // wave-local write; same-wave read below
    const int r = wave * 16 + lane;
    int j = (int)plist[row0 + r];
    jrows[r] = j;
    segs[r] = (int)unq_inv[j];
  }

  // ---- stage 0: features + bn0 + layer1 (scalar fp32); 4 lanes/row, wave-local rows ----
  {
    const int r = wave * 16 + (lane >> 2), part = lane & 3;
    const int sj = shuf[jrows[r]];
    const float PI_F = 3.14159265358979323846f;
    const float minb[3] = {0.0f, -PI_F, -4.0f};
    const float maxb[3] = {50.0f, PI_F, 2.0f};
    const float gm1[3]  = {479.0f, 359.0f, 31.0f};
    float x0[9];
    #pragma unroll
    for (int d = 0; d < 3; ++d) {
      float itv = (maxb[d] - minb[d]) / gm1[d];
      float x   = xyz[(size_t)sj * 3 + d];
      float cl  = fminf(fmaxf(x, minb[d]), maxb[d]);
      float fi  = floorf((cl - minb[d]) / itv);
      float center = (fi + 0.5f) * itv + minb[d];
      x0[d] = (x - center) * s0[d] + t0[d];           // bn0 folded
    }
    #pragma unroll
    for (int d = 0; d < 6; ++d) x0[3 + d] = ptfea[(size_t)sj * 6 + d] * s0[3 + d] + t0[3 + d];
    unsigned short h[16];
    #pragma unroll
    for (int ci = 0; ci < 16; ++ci) {
      float acc = be1[part * 16 + ci];
      #pragma unroll
      for (int k = 0; k < 9; ++k) acc += x0[k] * w1e[k * 64 + part * 16 + ci];
      h[ci] = f2bf(fmaxf(acc, 0.0f));
    }
    *(short8*)&buf[r * PA + part * 16]     = *(short8*)&h[0];
    *(short8*)&buf[r * PA + part * 16 + 8] = *(short8*)&h[8];
  }
  __syncthreads();

  // ---- L2 [64->128] cols 0->136 (disjoint: no mid barrier); L3 [128->256] 136->0; L4 in-place ----
  gemm_stage< 64, 128, true,  false>(w2t, be2, buf,       buf + 136, wave, l15, quad);
  gemm_stage<128, 256, true,  true >(w3t, be3, buf + 136, buf,       wave, l15, quad);
  gemm_stage<256, 256, false, true >(w4t, b4,  buf,       buf,       wave, l15, quad);

  // ---- wave 0: run analysis + compact multi-run list ----
  if (tid < 64) {
    const int r = tid;
    bool lead = (r == 0) || (segs[r] != segs[r - 1]);
    s_lead[r] = lead ? 1 : 0;
    unsigned char comp = 0;
    int e = r + 1;
    if (lead) {
      atomicMax(&s_alast, r);
      while (e < 64 && segs[e] == segs[r]) ++e;
      const unsigned s = (unsigned)segs[r];
      comp = (offv[s] == (unsigned)(row0 + r) && offv[s] + cnt[s] == (unsigned)(row0 + e)) ? 1 : 0;
    }
    s_comp[r] = comp;
    const bool multi = lead && (e - r) > 1;
    unsigned long long mm = __ballot(multi);
    if (multi) {
      int idx = (int)__popcll(mm & ((1ull << r) - 1ull));
      s_runs[idx] = (unsigned short)((r << 8) | e);
    }
    if (tid == 0) s_nrun = (int)__popcll(mm);
  }
  __syncthreads();

  // ---- sparse fixup: per multi-run, column-thread computes run max into the leader row ----
  {
    const int n = s_nrun;
    for (int i = 0; i < n; ++i) {
      const int re = s_runs[i];
      const int r = re >> 8, e = re & 255;
      float m = bf2f(buf[r * PA + tid]);
      for (int rr = r + 1; rr < e; ++rr) m = fmaxf(m, bf2f(buf[rr * PA + tid]));
      buf[r * PA + tid] = f2bf(m);
    }
  }
  __syncthreads();

  // ---- boundary partials (first/last incomplete runs; rows 0 and alast are leaders) ----
  {
    const int c = tid;
    const int alast = s_alast;
    const size_t b2 = (size_t)blockIdx.x * 2;
    if (!s_comp[0])     partials[b2 * 256 + c]       = buf[0 * PA + c];
    if (!s_comp[alast]) partials[(b2 + 1) * 256 + c] = buf[alast * PA + c];
  }

  // ---- compression: pooled[rows wave*16+l15, 256] @ wct^T; swapped-D -> float4 stores ----
  {
    const unsigned short* wp = wct + l15 * 256 + quad * 8;
    f32x4 acc = (f32x4){0.f, 0.f, 0.f, 0.f};
    #pragma unroll
    for (int kc = 0; kc < 256; kc += 32) {
      bf16x8 w = __builtin_bit_cast(bf16x8, *(const short8*)(wp + kc));
      bf16x8 x = __builtin_bit_cast(bf16x8, *(const short8*)&buf[(wave * 16 + l15) * PA + kc + quad * 8]);
      acc = __builtin_amdgcn_mfma_f32_16x16x32_bf16(w, x, acc, 0, 0, 0);
    }
    const int r1 = wave * 16 + l15;                  // pooled row (D col = l15)
    if (s_lead[r1] && s_comp[r1]) {
      const f32x4 bcv = *(const f32x4*)&bc[quad * 4];
      f32x4 v;
      #pragma unroll
      for (int r = 0; r < 4; ++r) v[r] = fmaxf(acc[r] + bcv[r], 0.f);   // cols quad*4+r
      *(f32x4*)&out_pooled[(size_t)segs[r1] * 16 + quad * 4] = v;
    }
  }
}

// ---------------- merge block-spanning segments from partials ----
__global__ __launch_bounds__(256) void merge_kernel(
    const unsigned* __restrict__ plist, const unsigned* __restrict__ unq_inv,
    const unsigned* __restrict__ offv, const unsigned* __restrict__ cnt,
    const unsigned short* __restrict__ partials,
    const float* __restrict__ wc, const float* __restrict__ bc,
    float* __restrict__ out_pooled)
{
  __shared__ float pooled[256];
  __shared__ float psum[256];
  const int b = blockIdx.x;
  const unsigned s = unq_inv[plist[(size_t)b * 64 + 63]];
  const unsigned o = offv[s], e = o + cnt[s];
  if ((o >> 6) != (unsigned)b) return;              // owner = block where segment starts
  if (e <= (unsigned)(b + 1) * 64) return;          // doesn't span a boundary
  const int B1 = (int)((e - 1) >> 6);
  const int c = threadIdx.x;
  float m = bf2f(partials[((size_t)2 * b + 1) * 256 + c]);    // head partial (last run of b)
  for (int bb = b + 1; bb <= B1; ++bb)
    m = fmaxf(m, bf2f(partials[(size_t)2 * bb * 256 + c]));   // tails (first run of bb)
  pooled[c] = m;
  __syncthreads();
  const int co = c & 15, kg = c >> 4;
  float p = 0.f;
  #pragma unroll
  for (int k = kg * 16; k < kg * 16 + 16; ++k) p += pooled[k] * wc[k * 16 + co];
  psum[c] = p;
  __syncthreads();
  if (c < 16) {
    float acc = bc[c];
    #pragma unroll
    for (int g = 0; g < 16; ++g) acc += psum[g * 16 + c];
    out_pooled[(size_t)s * 16 + c] = fmaxf(acc, 0.f);
  }
}

extern "C" void kernel_launch(void* const* d_in, const int* in_sizes, int n_in,
                              void* d_out, int out_size, void* d_ws, size_t ws_size,
                              hipStream_t stream)
{
  const float* pt_fea = (const float*)d_in[0];
  const float* xyz    = (const float*)d_in[1];
  const int*   bidx   = (const int*)d_in[2];
  const int*   ptlab  = (const int*)d_in[3];
  const int*   shuf   = (const int*)d_in[4];
  const float* bng0 = (const float*)d_in[5],  *bnb0 = (const float*)d_in[6],  *bnm0 = (const float*)d_in[7],  *bnv0 = (const float*)d_in[8];
  const float* bng1 = (const float*)d_in[9],  *bnb1 = (const float*)d_in[10], *bnm1 = (const float*)d_in[11], *bnv1 = (const float*)d_in[12];
  const float* bng2 = (const float*)d_in[13], *bnb2 = (const float*)d_in[14], *bnm2 = (const float*)d_in[15], *bnv2 = (const float*)d_in[16];
  const float* bng3 = (const float*)d_in[17], *bnb3 = (const float*)d_in[18], *bnm3 = (const float*)d_in[19], *bnv3 = (const float*)d_in[20];
  const float* w1 = (const float*)d_in[21], *b1 = (const float*)d_in[22];
  const float* w2 = (const float*)d_in[23], *b2 = (const float*)d_in[24];
  const float* w3 = (const float*)d_in[25], *b3 = (const float*)d_in[26];
  const float* w4 = (const float*)d_in[27], *b4 = (const float*)d_in[28];
  const float* wc = (const float*)d_in[29], *bc = (const float*)d_in[30];

  float* out        = (float*)d_out;                // outputs int64/f32/int32 -> float32 buffer
  float* out_unq    = out;                          // [240000]
  float* out_pooled = out + 240000;                 // [240000,16]
  float* out_lab    = out + 4080000;                // [2,480,360,32]
  float* out_cat    = out + 15139200;               // [240000,4]

  char* wsb = (char*)d_ws;
  size_t o = 0;
  auto alloc = [&](size_t bytes) -> void* { void* p = wsb + o; o = (o + bytes + 255) & ~(size_t)255; return p; };
  // zero-init region (single memset): bitmap | cnt | counts
  unsigned long long* bitmap = (unsigned long long*)alloc((size_t)NWORDS * 8);
  unsigned* cnt    = (unsigned*)alloc((size_t)N_PTS * 4);
  unsigned* counts = (unsigned*)alloc((size_t)N_PTS * 10 * 4);
  const size_t zero_bytes = o;
  float* s0  = (float*)alloc(9 * 4);
  float* t0  = (float*)alloc(9 * 4);
  float* w1e = (float*)alloc(576 * 4);
  float* be1 = (float*)alloc(64 * 4);
  float* be2 = (float*)alloc(128 * 4);
  float* be3 = (float*)alloc(256 * 4);
  unsigned short* w2t = (unsigned short*)alloc(8192 * 2);
  unsigned short* w3t = (unsigned short*)alloc(32768 * 2);
  unsigned short* w4t = (unsigned short*)alloc(65536 * 2);
  unsigned short* wct = (unsigned short*)alloc(4096 * 2);
  unsigned* flatkeys = (unsigned*)alloc((size_t)N_PTS * 4);
  unsigned* unq_inv  = (unsigned*)alloc((size_t)N_PTS * 4);
  unsigned* unqvals  = (unsigned*)alloc((size_t)N_PTS * 4);
  unsigned* offv     = (unsigned*)alloc((size_t)N_PTS * 4);
  unsigned* cur      = (unsigned*)alloc((size_t)N_PTS * 4);
  unsigned* plist    = (unsigned*)alloc((size_t)N_PTS * 4);
  unsigned* wordpref = (unsigned*)alloc((size_t)NWORDS * 4);
  unsigned* bsumA    = (unsigned*)alloc(NB_WORD * 4);
  unsigned* bsumB    = (unsigned*)alloc(NB_PT * 4);
  unsigned short* partials = (unsigned short*)alloc((size_t)NBLK_MLP * 2 * 256 * 2);
  // total ~22.8 MB

  hipMemsetAsync(bitmap, 0, zero_bytes, stream);
  hipMemsetAsync(out_lab, 0, (size_t)NV * 4, stream);       // float 0.0f == all-zero bytes

  prep_vox_kernel<<<256 + NB_PT, 256, 0, stream>>>(
      bng0, bnb0, bnm0, bnv0, bng1, bnb1, bnm1, bnv1,
      bng2, bnb2, bnm2, bnv2, bng3, bnb3, bnm3, bnv3,
      w1, b1, w2, b2, w3, b3, w4, wc,
      s0, t0, w1e, be1, be2, be3, w2t, w3t, w4t, wct,
      xyz, bidx, flatkeys, bitmap, out_cat, out_unq);
  reduce_words<<<NB_WORD, 256, 0, stream>>>(bitmap, bsumA);
  scan_small<<<1, 1024, 0, stream>>>(bsumA, NB_WORD);
  scatter_unq<<<NB_WORD, 256, 0, stream>>>(bitmap, bsumA, wordpref, unqvals, out_unq);
  inv_kernel<<<NB_PT, 256, 0, stream>>>(flatkeys, bitmap, wordpref, ptlab, unq_inv, cnt, counts);
  reduce_cnt<<<NB_PT, 256, 0, stream>>>(cnt, bsumB);
  scan_small<<<1, 1024, 0, stream>>>(bsumB, NB_PT);
  scan_cnt<<<NB_PT, 256, 0, stream>>>(cnt, bsumB, offv, cur);
  plist_labels_kernel<<<NB_PT, 256, 0, stream>>>(unq_inv, cur, plist, cnt, counts, unqvals, bc,
                                                 out_lab, out_pooled);
  mlp_pool_kernel<<<NBLK_MLP, 256, 0, stream>>>(pt_fea, xyz, shuf, plist, unq_inv, offv, cnt,
                                                s0, t0, w1e, be1, w2t, be2, w3t, be3, w4t, b4,
                                                wct, bc, partials, out_pooled);
  merge_kernel<<<NBLK_MLP, 256, 0, stream>>>(plist, unq_inv, offv, cnt, partials, wc, bc, out_pooled);
}

// Round 11
// 352.049 us; speedup vs baseline: 2.2972x; 1.0496x over previous
//
#include <hip/hip_runtime.h>
#include <stdint.h>

#define N_PTS 240000
#define NV    11059200      // 2*480*360*32 voxels
#define NWORDS 172800       // NV/64 bitmap words
#define NB_PT 938           // ceil(N_PTS/256)
#define NB_WORD 675         // NWORDS/256 (exact)
#define NBLK_MLP 3750       // N_PTS/64
#define PA 264              // LDS row pitch (shorts)

typedef __bf16 bf16x8 __attribute__((ext_vector_type(8)));
typedef short  short8 __attribute__((ext_vector_type(8)));
typedef float  f32x4  __attribute__((ext_vector_type(4)));

__device__ __forceinline__ unsigned short f2bf(float f) {
  unsigned u = __builtin_bit_cast(unsigned, f);
  return (unsigned short)((u + 0x7FFFu + ((u >> 16) & 1u)) >> 16);   // RNE
}
__device__ __forceinline__ float bf2f(unsigned short h) {
  unsigned u = ((unsigned)h) << 16;
  return __builtin_bit_cast(float, u);
}

__device__ __forceinline__ unsigned block_sum(unsigned v, unsigned* s4, int t) {
  #pragma unroll
  for (int o = 32; o; o >>= 1) v += __shfl_down(v, o);
  if ((t & 63) == 0) s4[t >> 6] = v;
  __syncthreads();
  unsigned r = s4[0] + s4[1] + s4[2] + s4[3];
  __syncthreads();
  return r;
}

// ---------------- fused: weight prep (blocks 0..255) + per-point voxelize (blocks 256..1193) ----
__global__ void prep_vox_kernel(
    const float* __restrict__ bng0, const float* __restrict__ bnb0, const float* __restrict__ bnm0, const float* __restrict__ bnv0,
    const float* __restrict__ bng1, const float* __restrict__ bnb1, const float* __restrict__ bnm1, const float* __restrict__ bnv1,
    const float* __restrict__ bng2, const float* __restrict__ bnb2, const float* __restrict__ bnm2, const float* __restrict__ bnv2,
    const float* __restrict__ bng3, const float* __restrict__ bnb3, const float* __restrict__ bnm3, const float* __restrict__ bnv3,
    const float* __restrict__ w1, const float* __restrict__ b1,
    const float* __restrict__ w2, const float* __restrict__ b2,
    const float* __restrict__ w3, const float* __restrict__ b3,
    const float* __restrict__ w4, const float* __restrict__ wc,
    float* __restrict__ s0, float* __restrict__ t0, float* __restrict__ w1e, float* __restrict__ be1,
    float* __restrict__ be2, float* __restrict__ be3,
    unsigned short* __restrict__ w2t, unsigned short* __restrict__ w3t, unsigned short* __restrict__ w4t,
    unsigned short* __restrict__ wct,
    const float* __restrict__ xyz, const int* __restrict__ bidx,
    unsigned* __restrict__ flatkeys, unsigned long long* __restrict__ bitmap,
    float* __restrict__ out_cat, float* __restrict__ out_unq)
{
  if (blockIdx.x < 256) {
    const int id = blockIdx.x * 256 + threadIdx.x;   // covers 65536 exactly
    { int c = id >> 8, k = id & 255; w4t[c * 256 + k] = f2bf(w4[k * 256 + c]); }
    if (id < 32768) { int c = id >> 7, k = id & 127;
      float s = bng3[c] * rsqrtf(bnv3[c] + 1e-5f);
      w3t[c * 128 + k] = f2bf(w3[k * 256 + c] * s); }
    if (id < 8192) { int c = id >> 6, k = id & 63;
      float s = bng2[c] * rsqrtf(bnv2[c] + 1e-5f);
      w2t[c * 64 + k] = f2bf(w2[k * 128 + c] * s); }
    if (id < 4096) { int c = id >> 8, k = id & 255;
      wct[c * 256 + k] = f2bf(wc[k * 16 + c]); }     // wc transposed [16][256]
    if (id < 576) { int k = id / 64, c = id % 64;
      float s = bng1[c] * rsqrtf(bnv1[c] + 1e-5f);
      w1e[k * 64 + c] = w1[k * 64 + c] * s; }
    if (id < 64)  { float s = bng1[id] * rsqrtf(bnv1[id] + 1e-5f); be1[id] = (b1[id] - bnm1[id]) * s + bnb1[id]; }
    if (id < 128) { float s = bng2[id] * rsqrtf(bnv2[id] + 1e-5f); be2[id] = (b2[id] - bnm2[id]) * s + bnb2[id]; }
    if (id < 256) { float s = bng3[id] * rsqrtf(bnv3[id] + 1e-5f); be3[id] = (b3[id] - bnm3[id]) * s + bnb3[id]; }
    if (id < 9)   { float s = bng0[id] * rsqrtf(bnv0[id] + 1e-5f); s0[id] = s; t0[id] = bnb0[id] - bnm0[id] * s; }
    return;
  }
  const int j = (blockIdx.x - 256) * 256 + threadIdx.x;
  if (j >= N_PTS) return;
  out_unq[j] = -1.0f;                               // jnp.unique fill_value
  const float PI_F = 3.14159265358979323846f;       // == float32(np.pi)
  const float minb[3] = {0.0f, -PI_F, -4.0f};
  const float maxb[3] = {50.0f, PI_F, 2.0f};
  const float gm1[3]  = {479.0f, 359.0f, 31.0f};
  int ind[3];
  #pragma unroll
  for (int d = 0; d < 3; ++d) {
    float itv = (maxb[d] - minb[d]) / gm1[d];       // IEEE fp32 div (no fast-math)
    float x  = xyz[(size_t)j * 3 + d];
    float cl = fminf(fmaxf(x, minb[d]), maxb[d]);
    ind[d] = (int)floorf((cl - minb[d]) / itv);
  }
  const int bi = bidx[j];
  const unsigned flat = ((unsigned)(bi * 480 + ind[0]) * 360u + (unsigned)ind[1]) * 32u + (unsigned)ind[2];
  flatkeys[j] = flat;
  atomicOr(&bitmap[flat >> 6], 1ull << (flat & 63u));
  float* oc = out_cat + (size_t)j * 4;
  oc[0] = (float)bi; oc[1] = (float)ind[0]; oc[2] = (float)ind[1]; oc[3] = (float)ind[2];
}

// ---------------- per-block popcount totals ----
__global__ void reduce_words(const unsigned long long* __restrict__ bm, unsigned* __restrict__ bsums) {
  __shared__ unsigned sh[256];
  const int w = blockIdx.x * 256 + threadIdx.x;     // exact coverage
  sh[threadIdx.x] = (unsigned)__popcll(bm[w]);
  __syncthreads();
  for (int s = 128; s > 0; s >>= 1) { if (threadIdx.x < s) sh[threadIdx.x] += sh[threadIdx.x + s]; __syncthreads(); }
  if (threadIdx.x == 0) bsums[blockIdx.x] = sh[0];
}

// ---------------- unique scatter w/ inline exclusive prefix (bsums are RAW totals) ----
__global__ __launch_bounds__(256) void scatter_unq(
    const unsigned long long* __restrict__ bm, const unsigned* __restrict__ bsums,
    unsigned* __restrict__ wordpref, unsigned* __restrict__ unqvals, float* __restrict__ out_unq)
{
  __shared__ unsigned sh[256];
  __shared__ unsigned s4[4];
  const int t = threadIdx.x, b = blockIdx.x;
  const int w = b * 256 + t;
  unsigned long long word = bm[w];
  unsigned own = (unsigned)__popcll(word);
  sh[t] = own; __syncthreads();
  for (int off = 1; off < 256; off <<= 1) {
    unsigned v = (t >= off) ? sh[t - off] : 0u;
    __syncthreads(); sh[t] += v; __syncthreads();
  }
  unsigned v = 0;                                   // brute-force prefix over L2-hot totals
  for (int i = t; i < b; i += 256) v += bsums[i];
  const unsigned excl = block_sum(v, s4, t);
  unsigned r = excl + sh[t] - own;                  // global exclusive prefix
  wordpref[w] = r;
  while (word) {
    int bit = __builtin_ctzll(word);
    unsigned id = (unsigned)w * 64u + (unsigned)bit;
    unqvals[r] = id;
    out_unq[r] = (float)id;                         // exact: id < 2^24
    ++r;
    word &= word - 1;
  }
}

// ---------------- inverse indices + segment sizes (histogram removed: labels fused downstream) ----
__global__ void inv_kernel(const unsigned* __restrict__ flatkeys, const unsigned long long* __restrict__ bm,
                           const unsigned* __restrict__ wordpref,
                           unsigned* __restrict__ unq_inv, unsigned* __restrict__ cnt) {
  const int j = blockIdx.x * 256 + threadIdx.x;
  if (j >= N_PTS) return;
  const unsigned f = flatkeys[j];
  const unsigned w = f >> 6, b = f & 63u;
  const unsigned r = wordpref[w] + (unsigned)__popcll(bm[w] & ((1ull << b) - 1ull));
  unq_inv[j] = r;
  atomicAdd(&cnt[r], 1u);
}

// ---------------- per-block cnt totals ----
__global__ void reduce_cnt(const unsigned* __restrict__ cnt, unsigned* __restrict__ bsums) {
  __shared__ unsigned sh[256];
  const int j = blockIdx.x * 256 + threadIdx.x;
  sh[threadIdx.x] = (j < N_PTS) ? cnt[j] : 0u;
  __syncthreads();
  for (int s = 128; s > 0; s >>= 1) { if (threadIdx.x < s) sh[threadIdx.x] += sh[threadIdx.x + s]; __syncthreads(); }
  if (threadIdx.x == 0) bsums[blockIdx.x] = sh[0];
}

// ---------------- CSR offsets w/ inline exclusive prefix (bsums are RAW totals) ----
__global__ __launch_bounds__(256) void scan_cnt(
    const unsigned* __restrict__ cnt, const unsigned* __restrict__ bsums,
    unsigned* __restrict__ off, unsigned* __restrict__ cur)
{
  __shared__ unsigned sh[256];
  __shared__ unsigned s4[4];
  const int t = threadIdx.x, b = blockIdx.x;
  const int j = b * 256 + t;
  unsigned own = (j < N_PTS) ? cnt[j] : 0u;
  sh[t] = own; __syncthreads();
  for (int o = 1; o < 256; o <<= 1) {
    unsigned v = (t >= o) ? sh[t - o] : 0u;
    __syncthreads(); sh[t] += v; __syncthreads();
  }
  unsigned v = 0;
  for (int i = t; i < b; i += 256) v += bsums[i];
  const unsigned excl = block_sum(v, s4, t);
  if (j < N_PTS) { unsigned e = excl + sh[t] - own; off[j] = e; cur[j] = e; }
}

// ---------------- plist scatter + empty-segment pooled fill ----
__global__ void plist_fill_kernel(const unsigned* __restrict__ unq_inv, unsigned* __restrict__ cur,
                                  unsigned* __restrict__ plist,
                                  const unsigned* __restrict__ cnt, const float* __restrict__ bc,
                                  float* __restrict__ out_pooled) {
  const int j = blockIdx.x * 256 + threadIdx.x;
  if (j >= N_PTS) return;
  plist[atomicAdd(&cur[unq_inv[j]], 1u)] = (unsigned)j;
  if (cnt[j] == 0) {
    #pragma unroll
    for (int c = 0; c < 16; ++c) out_pooled[(size_t)j * 16 + c] = fmaxf(bc[c], 0.f);
  }
}

// ---- block-wide GEMM stage, column-strip waves, SWAPPED-D epilogue (b64 LDS writes) ----
// mfma(w_frag, x_frag): D row'=quad*4+r = OUT COLUMN, D col=l15 = OUT ROW (within mt tile).
// All k-loop LDS reads precede the (optional) mid barrier -> in-place/overlapping out is safe.
template<int K, int C, bool RELU, bool MIDB>
__device__ __forceinline__ void gemm_stage(
    const unsigned short* __restrict__ Wt,     // [C][K] bf16, global (L2-hot)
    const float* __restrict__ bias,            // [C]
    const unsigned short* in,                  // LDS, pitch PA (col-offset base)
    unsigned short* outp,                      // LDS, pitch PA (may overlap in)
    int wave, int l15, int quad)
{
  constexpr int KC = K / 32;
  constexpr int NT = C / 64;                   // 16-col tiles per wave (weights read ONCE/block)
  f32x4 acc[4][NT];
  #pragma unroll
  for (int mt = 0; mt < 4; ++mt)
    #pragma unroll
    for (int nt = 0; nt < NT; ++nt) acc[mt][nt] = (f32x4){0.f, 0.f, 0.f, 0.f};
  const unsigned short* wp[NT];
  #pragma unroll
  for (int nt = 0; nt < NT; ++nt)
    wp[nt] = Wt + (size_t)(wave * 16 * NT + nt * 16 + l15) * K + quad * 8;
  #pragma unroll
  for (int kc = 0; kc < KC; ++kc) {
    bf16x8 b[NT];
    #pragma unroll
    for (int nt = 0; nt < NT; ++nt)
      b[nt] = __builtin_bit_cast(bf16x8, *(const short8*)(wp[nt] + kc * 32));
    #pragma unroll
    for (int mt = 0; mt < 4; ++mt) {
      bf16x8 a = __builtin_bit_cast(bf16x8, *(const short8*)&in[(mt * 16 + l15) * PA + kc * 32 + quad * 8]);
      #pragma unroll
      for (int nt = 0; nt < NT; ++nt)
        acc[mt][nt] = __builtin_amdgcn_mfma_f32_16x16x32_bf16(b[nt], a, acc[mt][nt], 0, 0, 0);
    }
  }
  if (MIDB) __syncthreads();                   // reads drained before overlapping writes
  #pragma unroll
  for (int mt = 0; mt < 4; ++mt)
    #pragma unroll
    for (int nt = 0; nt < NT; ++nt) {
      const int cbase = wave * 16 * NT + nt * 16 + quad * 4;
      const f32x4 bs = *(const f32x4*)&bias[cbase];
      unsigned short h[4];
      #pragma unroll
      for (int r = 0; r < 4; ++r) {
        float y = acc[mt][nt][r] + bs[r];
        if (RELU) y = fmaxf(y, 0.f);
        h[r] = f2bf(y);
      }
      uint2 pk; pk.x = (unsigned)h[0] | ((unsigned)h[1] << 16);
      pk.y = (unsigned)h[2] | ((unsigned)h[3] << 16);
      *(uint2*)&outp[(mt * 16 + l15) * PA + cbase] = pk;   // ds_write_b64
    }
  __syncthreads();
}

// ---------------- fused MLP + sparse segment-max fixup + compression + labels ----
__global__ __launch_bounds__(256, 4) void mlp_pool_kernel(
    const float* __restrict__ ptfea, const float* __restrict__ xyz, const int* __restrict__ shuf,
    const unsigned* __restrict__ plist, const unsigned* __restrict__ unq_inv,
    const unsigned* __restrict__ offv, const unsigned* __restrict__ cnt,
    const int* __restrict__ ptlab, const unsigned* __restrict__ unqvals,
    const float* __restrict__ s0, const float* __restrict__ t0,
    const float* __restrict__ w1e, const float* __restrict__ be1,
    const unsigned short* __restrict__ w2t, const float* __restrict__ be2,
    const unsigned short* __restrict__ w3t, const float* __restrict__ be3,
    const unsigned short* __restrict__ w4t, const float* __restrict__ b4,
    const unsigned short* __restrict__ wct, const float* __restrict__ bc,
    unsigned short* __restrict__ partials, float* __restrict__ out_pooled,
    float* __restrict__ out_lab)
{
  __shared__ __align__(16) unsigned short buf[64 * PA];
  __shared__ int segs[64];
  __shared__ int jrows[64];
  __shared__ int s_alast;
  __shared__ int s_nrun;
  __shared__ unsigned short s_runs[32];              // (r<<8)|e for runs with len>1
  __shared__ unsigned char s_lead[64], s_comp[64];
  const int tid  = threadIdx.x;
  const int wave = tid >> 6, lane = tid & 63;
  const int l15 = lane & 15, quad = lane >> 4;
  const int row0 = blockIdx.x * 64;

  if (tid == 0) { s_alast = 0; s_nrun = 0; }
  if (lane < 16) {                                   // wave-local write; same-wave read below
    const int r = wave * 16 + lane;
    int j = (int)plist[row0 + r];
    jrows[r] = j;
    segs[r] = (int)unq_inv[j];
  }

  // ---- stage 0: features + bn0 + layer1 (scalar fp32); 4 lanes/row, wave-local rows ----
  {
    const int r = wave * 16 + (lane >> 2), part = lane & 3;
    const int sj = shuf[jrows[r]];
    const float PI_F = 3.14159265358979323846f;
    const float minb[3] = {0.0f, -PI_F, -4.0f};
    const float maxb[3] = {50.0f, PI_F, 2.0f};
    const float gm1[3]  = {479.0f, 359.0f, 31.0f};
    float x0[9];
    #pragma unroll
    for (int d = 0; d < 3; ++d) {
      float itv = (maxb[d] - minb[d]) / gm1[d];
      float x   = xyz[(size_t)sj * 3 + d];
      float cl  = fminf(fmaxf(x, minb[d]), maxb[d]);
      float fi  = floorf((cl - minb[d]) / itv);
      float center = (fi + 0.5f) * itv + minb[d];
      x0[d] = (x - center) * s0[d] + t0[d];           // bn0 folded
    }
    #pragma unroll
    for (int d = 0; d < 6; ++d) x0[3 + d] = ptfea[(size_t)sj * 6 + d] * s0[3 + d] + t0[3 + d];
    unsigned short h[16];
    #pragma unroll
    for (int ci = 0; ci < 16; ++ci) {
      float acc = be1[part * 16 + ci];
      #pragma unroll
      for (int k = 0; k < 9; ++k) acc += x0[k] * w1e[k * 64 + part * 16 + ci];
      h[ci] = f2bf(fmaxf(acc, 0.0f));
    }
    *(short8*)&buf[r * PA + part * 16]     = *(short8*)&h[0];
    *(short8*)&buf[r * PA + part * 16 + 8] = *(short8*)&h[8];
  }
  __syncthreads();

  // ---- L2 [64->128] cols 0->136 (disjoint: no mid barrier); L3 [128->256] 136->0; L4 in-place ----
  gemm_stage< 64, 128, true,  false>(w2t, be2, buf,       buf + 136, wave, l15, quad);
  gemm_stage<128, 256, true,  true >(w3t, be3, buf + 136, buf,       wave, l15, quad);
  gemm_stage<256, 256, false, true >(w4t, b4,  buf,       buf,       wave, l15, quad);

  // ---- wave 0: run analysis + compact multi-run list + labels for complete runs ----
  if (tid < 64) {
    const int r = tid;
    bool lead = (r == 0) || (segs[r] != segs[r - 1]);
    s_lead[r] = lead ? 1 : 0;
    unsigned char comp = 0;
    int e = r + 1;
    if (lead) {
      atomicMax(&s_alast, r);
      while (e < 64 && segs[e] == segs[r]) ++e;
      const unsigned s = (unsigned)segs[r];
      comp = (offv[s] == (unsigned)(row0 + r) && offv[s] + cnt[s] == (unsigned)(row0 + e)) ? 1 : 0;
    }
    s_comp[r] = comp;
    if (comp) {                                      // label argmax: first max = smallest label
      int bestl;
      if (e - r == 1) bestl = ptlab[jrows[r]];
      else {
        int bestc = 0; bestl = 32;
        for (int i = r; i < e; ++i) {
          const int li = ptlab[jrows[i]];
          int cc = 0;
          for (int k2 = r; k2 < e; ++k2) cc += (ptlab[jrows[k2]] == li) ? 1 : 0;
          if (cc > bestc || (cc == bestc && li < bestl)) { bestc = cc; bestl = li; }
        }
      }
      out_lab[unqvals[segs[r]]] = (float)bestl;
    }
    const bool multi = lead && (e - r) > 1;
    unsigned long long mm = __ballot(multi);
    if (multi) {
      int idx = (int)__popcll(mm & ((1ull << r) - 1ull));
      s_runs[idx] = (unsigned short)((r << 8) | e);
    }
    if (tid == 0) s_nrun = (int)__popcll(mm);
  }
  __syncthreads();

  // ---- sparse fixup: per multi-run, column-thread computes run max into the leader row ----
  {
    const int n = s_nrun;
    for (int i = 0; i < n; ++i) {
      const int re = s_runs[i];
      const int r = re >> 8, e = re & 255;
      float m = bf2f(buf[r * PA + tid]);
      for (int rr = r + 1; rr < e; ++rr) m = fmaxf(m, bf2f(buf[rr * PA + tid]));
      buf[r * PA + tid] = f2bf(m);
    }
  }
  __syncthreads();

  // ---- boundary partials (first/last incomplete runs; rows 0 and alast are leaders) ----
  {
    const int c = tid;
    const int alast = s_alast;
    const size_t b2 = (size_t)blockIdx.x * 2;
    if (!s_comp[0])     partials[b2 * 256 + c]       = buf[0 * PA + c];
    if (!s_comp[alast]) partials[(b2 + 1) * 256 + c] = buf[alast * PA + c];
  }

  // ---- compression: pooled[rows wave*16+l15, 256] @ wct^T; swapped-D -> float4 stores ----
  {
    const unsigned short* wp = wct + l15 * 256 + quad * 8;
    f32x4 acc = (f32x4){0.f, 0.f, 0.f, 0.f};
    #pragma unroll
    for (int kc = 0; kc < 256; kc += 32) {
      bf16x8 w = __builtin_bit_cast(bf16x8, *(const short8*)(wp + kc));
      bf16x8 x = __builtin_bit_cast(bf16x8, *(const short8*)&buf[(wave * 16 + l15) * PA + kc + quad * 8]);
      acc = __builtin_amdgcn_mfma_f32_16x16x32_bf16(w, x, acc, 0, 0, 0);
    }
    const int r1 = wave * 16 + l15;                  // pooled row (D col = l15)
    if (s_lead[r1] && s_comp[r1]) {
      const f32x4 bcv = *(const f32x4*)&bc[quad * 4];
      f32x4 v;
      #pragma unroll
      for (int r = 0; r < 4; ++r) v[r] = fmaxf(acc[r] + bcv[r], 0.f);   // cols quad*4+r
      *(f32x4*)&out_pooled[(size_t)segs[r1] * 16 + quad * 4] = v;
    }
  }
}

// ---------------- merge block-spanning segments from partials (+ their labels) ----
__global__ __launch_bounds__(256) void merge_kernel(
    const unsigned* __restrict__ plist, const unsigned* __restrict__ unq_inv,
    const unsigned* __restrict__ offv, const unsigned* __restrict__ cnt,
    const unsigned short* __restrict__ partials,
    const int* __restrict__ ptlab, const unsigned* __restrict__ unqvals,
    const float* __restrict__ wc, const float* __restrict__ bc,
    float* __restrict__ out_pooled, float* __restrict__ out_lab)
{
  __shared__ float pooled[256];
  __shared__ float psum[256];
  const int b = blockIdx.x;
  const unsigned s = unq_inv[plist[(size_t)b * 64 + 63]];
  const unsigned o = offv[s], e = o + cnt[s];
  if ((o >> 6) != (unsigned)b) return;              // owner = block where segment starts
  if (e <= (unsigned)(b + 1) * 64) return;          // doesn't span a boundary
  const int B1 = (int)((e - 1) >> 6);
  const int c = threadIdx.x;
  float m = bf2f(partials[((size_t)2 * b + 1) * 256 + c]);    // head partial (last run of b)
  for (int bb = b + 1; bb <= B1; ++bb)
    m = fmaxf(m, bf2f(partials[(size_t)2 * bb * 256 + c]));   // tails (first run of bb)
  pooled[c] = m;
  __syncthreads();
  const int co = c & 15, kg = c >> 4;
  float p = 0.f;
  #pragma unroll
  for (int k = kg * 16; k < kg * 16 + 16; ++k) p += pooled[k] * wc[k * 16 + co];
  psum[c] = p;
  __syncthreads();
  if (c < 16) {
    float acc = bc[c];
    #pragma unroll
    for (int g = 0; g < 16; ++g) acc += psum[g * 16 + c];
    out_pooled[(size_t)s * 16 + c] = fmaxf(acc, 0.f);
  }
  if (c == 0) {                                     // label argmax over the spanning segment
    int bestc = 0, bestl = 32;
    for (unsigned i = o; i < e; ++i) {
      const int li = ptlab[plist[i]];
      int cc = 0;
      for (unsigned k2 = o; k2 < e; ++k2) cc += (ptlab[plist[k2]] == li) ? 1 : 0;
      if (cc > bestc || (cc == bestc && li < bestl)) { bestc = cc; bestl = li; }
    }
    out_lab[unqvals[s]] = (float)bestl;
  }
}

extern "C" void kernel_launch(void* const* d_in, const int* in_sizes, int n_in,
                              void* d_out, int out_size, void* d_ws, size_t ws_size,
                              hipStream_t stream)
{
  const float* pt_fea = (const float*)d_in[0];
  const float* xyz    = (const float*)d_in[1];
  const int*   bidx   = (const int*)d_in[2];
  const int*   ptlab  = (const int*)d_in[3];
  const int*   shuf   = (const int*)d_in[4];
  const float* bng0 = (const float*)d_in[5],  *bnb0 = (const float*)d_in[6],  *bnm0 = (const float*)d_in[7],  *bnv0 = (const float*)d_in[8];
  const float* bng1 = (const float*)d_in[9],  *bnb1 = (const float*)d_in[10], *bnm1 = (const float*)d_in[11], *bnv1 = (const float*)d_in[12];
  const float* bng2 = (const float*)d_in[13], *bnb2 = (const float*)d_in[14], *bnm2 = (const float*)d_in[15], *bnv2 = (const float*)d_in[16];
  const float* bng3 = (const float*)d_in[17], *bnb3 = (const float*)d_in[18], *bnm3 = (const float*)d_in[19], *bnv3 = (const float*)d_in[20];
  const float* w1 = (const float*)d_in[21], *b1 = (const float*)d_in[22];
  const float* w2 = (const float*)d_in[23], *b2 = (const float*)d_in[24];
  const float* w3 = (const float*)d_in[25], *b3 = (const float*)d_in[26];
  const float* w4 = (const float*)d_in[27], *b4 = (const float*)d_in[28];
  const float* wc = (const float*)d_in[29], *bc = (const float*)d_in[30];

  float* out        = (float*)d_out;                // outputs int64/f32/int32 -> float32 buffer
  float* out_unq    = out;                          // [240000]
  float* out_pooled = out + 240000;                 // [240000,16]
  float* out_lab    = out + 4080000;                // [2,480,360,32]
  float* out_cat    = out + 15139200;               // [240000,4]

  char* wsb = (char*)d_ws;
  size_t o = 0;
  auto alloc = [&](size_t bytes) -> void* { void* p = wsb + o; o = (o + bytes + 255) & ~(size_t)255; return p; };
  // zero-init region (single memset): bitmap | cnt
  unsigned long long* bitmap = (unsigned long long*)alloc((size_t)NWORDS * 8);
  unsigned* cnt    = (unsigned*)alloc((size_t)N_PTS * 4);
  const size_t zero_bytes = o;
  float* s0  = (float*)alloc(9 * 4);
  float* t0  = (float*)alloc(9 * 4);
  float* w1e = (float*)alloc(576 * 4);
  float* be1 = (float*)alloc(64 * 4);
  float* be2 = (float*)alloc(128 * 4);
  float* be3 = (float*)alloc(256 * 4);
  unsigned short* w2t = (unsigned short*)alloc(8192 * 2);
  unsigned short* w3t = (unsigned short*)alloc(32768 * 2);
  unsigned short* w4t = (unsigned short*)alloc(65536 * 2);
  unsigned short* wct = (unsigned short*)alloc(4096 * 2);
  unsigned* flatkeys = (unsigned*)alloc((size_t)N_PTS * 4);
  unsigned* unq_inv  = (unsigned*)alloc((size_t)N_PTS * 4);
  unsigned* unqvals  = (unsigned*)alloc((size_t)N_PTS * 4);
  unsigned* offv     = (unsigned*)alloc((size_t)N_PTS * 4);
  unsigned* cur      = (unsigned*)alloc((size_t)N_PTS * 4);
  unsigned* plist    = (unsigned*)alloc((size_t)N_PTS * 4);
  unsigned* wordpref = (unsigned*)alloc((size_t)NWORDS * 4);
  unsigned* bsumA    = (unsigned*)alloc(NB_WORD * 4);
  unsigned* bsumB    = (unsigned*)alloc(NB_PT * 4);
  unsigned short* partials = (unsigned short*)alloc((size_t)NBLK_MLP * 2 * 256 * 2);
  // total ~13 MB

  hipMemsetAsync(bitmap, 0, zero_bytes, stream);
  hipMemsetAsync(out_lab, 0, (size_t)NV * 4, stream);       // float 0.0f == all-zero bytes

  prep_vox_kernel<<<256 + NB_PT, 256, 0, stream>>>(
      bng0, bnb0, bnm0, bnv0, bng1, bnb1, bnm1, bnv1,
      bng2, bnb2, bnm2, bnv2, bng3, bnb3, bnm3, bnv3,
      w1, b1, w2, b2, w3, b3, w4, wc,
      s0, t0, w1e, be1, be2, be3, w2t, w3t, w4t, wct,
      xyz, bidx, flatkeys, bitmap, out_cat, out_unq);
  reduce_words<<<NB_WORD, 256, 0, stream>>>(bitmap, bsumA);
  scatter_unq<<<NB_WORD, 256, 0, stream>>>(bitmap, bsumA, wordpref, unqvals, out_unq);
  inv_kernel<<<NB_PT, 256, 0, stream>>>(flatkeys, bitmap, wordpref, unq_inv, cnt);
  reduce_cnt<<<NB_PT, 256, 0, stream>>>(cnt, bsumB);
  scan_cnt<<<NB_PT, 256, 0, stream>>>(cnt, bsumB, offv, cur);
  plist_fill_kernel<<<NB_PT, 256, 0, stream>>>(unq_inv, cur, plist, cnt, bc, out_pooled);
  mlp_pool_kernel<<<NBLK_MLP, 256, 0, stream>>>(pt_fea, xyz, shuf, plist, unq_inv, offv, cnt,
                                                ptlab, unqvals,
                                                s0, t0, w1e, be1, w2t, be2, w3t, be3, w4t, b4,
                                                wct, bc, partials, out_pooled, out_lab);
  merge_kernel<<<NBLK_MLP, 256, 0, stream>>>(plist, unq_inv, offv, cnt, partials,
                                             ptlab, unqvals, wc, bc, out_pooled, out_lab);
}

// Round 12
// 345.524 us; speedup vs baseline: 2.3406x; 1.0189x over previous
//
#include <hip/hip_runtime.h>
#include <stdint.h>

#define N_PTS 240000
#define NV    11059200      // 2*480*360*32 voxels
#define NWORDS 172800       // NV/64 bitmap words
#define NB_PT 938           // ceil(N_PTS/256)
#define NB_WORD 675         // NWORDS/256 (exact)
#define NBLK_MLP 3750       // N_PTS/64
#define PA 264              // LDS row pitch (shorts)

typedef __bf16 bf16x8 __attribute__((ext_vector_type(8)));
typedef short  short8 __attribute__((ext_vector_type(8)));
typedef float  f32x4  __attribute__((ext_vector_type(4)));

__device__ __forceinline__ unsigned short f2bf(float f) {
  unsigned u = __builtin_bit_cast(unsigned, f);
  return (unsigned short)((u + 0x7FFFu + ((u >> 16) & 1u)) >> 16);   // RNE
}
__device__ __forceinline__ float bf2f(unsigned short h) {
  unsigned u = ((unsigned)h) << 16;
  return __builtin_bit_cast(float, u);
}

__device__ __forceinline__ unsigned block_sum(unsigned v, unsigned* s4, int t) {
  #pragma unroll
  for (int o = 32; o; o >>= 1) v += __shfl_down(v, o);
  if ((t & 63) == 0) s4[t >> 6] = v;
  __syncthreads();
  unsigned r = s4[0] + s4[1] + s4[2] + s4[3];
  __syncthreads();
  return r;
}

// ---------------- fused: weight prep (blocks 0..255) + per-point voxelize (blocks 256..1193) ----
__global__ void prep_vox_kernel(
    const float* __restrict__ bng0, const float* __restrict__ bnb0, const float* __restrict__ bnm0, const float* __restrict__ bnv0,
    const float* __restrict__ bng1, const float* __restrict__ bnb1, const float* __restrict__ bnm1, const float* __restrict__ bnv1,
    const float* __restrict__ bng2, const float* __restrict__ bnb2, const float* __restrict__ bnm2, const float* __restrict__ bnv2,
    const float* __restrict__ bng3, const float* __restrict__ bnb3, const float* __restrict__ bnm3, const float* __restrict__ bnv3,
    const float* __restrict__ w1, const float* __restrict__ b1,
    const float* __restrict__ w2, const float* __restrict__ b2,
    const float* __restrict__ w3, const float* __restrict__ b3,
    const float* __restrict__ w4, const float* __restrict__ wc,
    float* __restrict__ s0, float* __restrict__ t0, float* __restrict__ w1e, float* __restrict__ be1,
    float* __restrict__ be2, float* __restrict__ be3,
    unsigned short* __restrict__ w2t, unsigned short* __restrict__ w3t, unsigned short* __restrict__ w4t,
    unsigned short* __restrict__ wct,
    const float* __restrict__ xyz, const int* __restrict__ bidx,
    unsigned* __restrict__ flatkeys, unsigned long long* __restrict__ bitmap,
    float* __restrict__ out_cat, float* __restrict__ out_unq)
{
  if (blockIdx.x < 256) {
    const int id = blockIdx.x * 256 + threadIdx.x;   // covers 65536 exactly
    { int c = id >> 8, k = id & 255; w4t[c * 256 + k] = f2bf(w4[k * 256 + c]); }
    if (id < 32768) { int c = id >> 7, k = id & 127;
      float s = bng3[c] * rsqrtf(bnv3[c] + 1e-5f);
      w3t[c * 128 + k] = f2bf(w3[k * 256 + c] * s); }
    if (id < 8192) { int c = id >> 6, k = id & 63;
      float s = bng2[c] * rsqrtf(bnv2[c] + 1e-5f);
      w2t[c * 64 + k] = f2bf(w2[k * 128 + c] * s); }
    if (id < 4096) { int c = id >> 8, k = id & 255;
      wct[c * 256 + k] = f2bf(wc[k * 16 + c]); }     // wc transposed [16][256]
    if (id < 576) { int k = id / 64, c = id % 64;
      float s = bng1[c] * rsqrtf(bnv1[c] + 1e-5f);
      w1e[k * 64 + c] = w1[k * 64 + c] * s; }
    if (id < 64)  { float s = bng1[id] * rsqrtf(bnv1[id] + 1e-5f); be1[id] = (b1[id] - bnm1[id]) * s + bnb1[id]; }
    if (id < 128) { float s = bng2[id] * rsqrtf(bnv2[id] + 1e-5f); be2[id] = (b2[id] - bnm2[id]) * s + bnb2[id]; }
    if (id < 256) { float s = bng3[id] * rsqrtf(bnv3[id] + 1e-5f); be3[id] = (b3[id] - bnm3[id]) * s + bnb3[id]; }
    if (id < 9)   { float s = bng0[id] * rsqrtf(bnv0[id] + 1e-5f); s0[id] = s; t0[id] = bnb0[id] - bnm0[id] * s; }
    return;
  }
  const int j = (blockIdx.x - 256) * 256 + threadIdx.x;
  if (j >= N_PTS) return;
  out_unq[j] = -1.0f;                               // jnp.unique fill_value
  const float PI_F = 3.14159265358979323846f;       // == float32(np.pi)
  const float minb[3] = {0.0f, -PI_F, -4.0f};
  const float maxb[3] = {50.0f, PI_F, 2.0f};
  const float gm1[3]  = {479.0f, 359.0f, 31.0f};
  int ind[3];
  #pragma unroll
  for (int d = 0; d < 3; ++d) {
    float itv = (maxb[d] - minb[d]) / gm1[d];       // IEEE fp32 div (no fast-math)
    float x  = xyz[(size_t)j * 3 + d];
    float cl = fminf(fmaxf(x, minb[d]), maxb[d]);
    ind[d] = (int)floorf((cl - minb[d]) / itv);
  }
  const int bi = bidx[j];
  const unsigned flat = ((unsigned)(bi * 480 + ind[0]) * 360u + (unsigned)ind[1]) * 32u + (unsigned)ind[2];
  flatkeys[j] = flat;
  atomicOr(&bitmap[flat >> 6], 1ull << (flat & 63u));
  float* oc = out_cat + (size_t)j * 4;
  oc[0] = (float)bi; oc[1] = (float)ind[0]; oc[2] = (float)ind[1]; oc[3] = (float)ind[2];
}

// ---------------- per-block popcount totals ----
__global__ void reduce_words(const unsigned long long* __restrict__ bm, unsigned* __restrict__ bsums) {
  __shared__ unsigned sh[256];
  const int w = blockIdx.x * 256 + threadIdx.x;     // exact coverage
  sh[threadIdx.x] = (unsigned)__popcll(bm[w]);
  __syncthreads();
  for (int s = 128; s > 0; s >>= 1) { if (threadIdx.x < s) sh[threadIdx.x] += sh[threadIdx.x + s]; __syncthreads(); }
  if (threadIdx.x == 0) bsums[blockIdx.x] = sh[0];
}

// ---------------- unique scatter w/ inline exclusive prefix (bsums are RAW totals) ----
__global__ __launch_bounds__(256) void scatter_unq(
    const unsigned long long* __restrict__ bm, const unsigned* __restrict__ bsums,
    unsigned* __restrict__ wordpref, unsigned* __restrict__ unqvals, float* __restrict__ out_unq)
{
  __shared__ unsigned sh[256];
  __shared__ unsigned s4[4];
  const int t = threadIdx.x, b = blockIdx.x;
  const int w = b * 256 + t;
  unsigned long long word = bm[w];
  unsigned own = (unsigned)__popcll(word);
  sh[t] = own; __syncthreads();
  for (int off = 1; off < 256; off <<= 1) {
    unsigned v = (t >= off) ? sh[t - off] : 0u;
    __syncthreads(); sh[t] += v; __syncthreads();
  }
  unsigned v = 0;                                   // brute-force prefix over L2-hot totals
  for (int i = t; i < b; i += 256) v += bsums[i];
  const unsigned excl = block_sum(v, s4, t);
  unsigned r = excl + sh[t] - own;                  // global exclusive prefix
  wordpref[w] = r;
  while (word) {
    int bit = __builtin_ctzll(word);
    unsigned id = (unsigned)w * 64u + (unsigned)bit;
    unqvals[r] = id;
    out_unq[r] = (float)id;                         // exact: id < 2^24
    ++r;
    word &= word - 1;
  }
}

// ---------------- inverse indices + segment sizes ----
__global__ void inv_kernel(const unsigned* __restrict__ flatkeys, const unsigned long long* __restrict__ bm,
                           const unsigned* __restrict__ wordpref,
                           unsigned* __restrict__ unq_inv, unsigned* __restrict__ cnt) {
  const int j = blockIdx.x * 256 + threadIdx.x;
  if (j >= N_PTS) return;
  const unsigned f = flatkeys[j];
  const unsigned w = f >> 6, b = f & 63u;
  const unsigned r = wordpref[w] + (unsigned)__popcll(bm[w] & ((1ull << b) - 1ull));
  unq_inv[j] = r;
  atomicAdd(&cnt[r], 1u);
}

// ---------------- per-block cnt totals ----
__global__ void reduce_cnt(const unsigned* __restrict__ cnt, unsigned* __restrict__ bsums) {
  __shared__ unsigned sh[256];
  const int j = blockIdx.x * 256 + threadIdx.x;
  sh[threadIdx.x] = (j < N_PTS) ? cnt[j] : 0u;
  __syncthreads();
  for (int s = 128; s > 0; s >>= 1) { if (threadIdx.x < s) sh[threadIdx.x] += sh[threadIdx.x + s]; __syncthreads(); }
  if (threadIdx.x == 0) bsums[blockIdx.x] = sh[0];
}

// ---------------- CSR offsets w/ inline exclusive prefix (bsums are RAW totals) ----
__global__ __launch_bounds__(256) void scan_cnt(
    const unsigned* __restrict__ cnt, const unsigned* __restrict__ bsums,
    unsigned* __restrict__ off, unsigned* __restrict__ cur)
{
  __shared__ unsigned sh[256];
  __shared__ unsigned s4[4];
  const int t = threadIdx.x, b = blockIdx.x;
  const int j = b * 256 + t;
  unsigned own = (j < N_PTS) ? cnt[j] : 0u;
  sh[t] = own; __syncthreads();
  for (int o = 1; o < 256; o <<= 1) {
    unsigned v = (t >= o) ? sh[t - o] : 0u;
    __syncthreads(); sh[t] += v; __syncthreads();
  }
  unsigned v = 0;
  for (int i = t; i < b; i += 256) v += bsums[i];
  const unsigned excl = block_sum(v, s4, t);
  if (j < N_PTS) { unsigned e = excl + sh[t] - own; off[j] = e; cur[j] = e; }
}

// ---------------- plist scatter (packed seg<<32|j) + empty-segment pooled fill ----
__global__ void plist_fill_kernel(const unsigned* __restrict__ unq_inv, unsigned* __restrict__ cur,
                                  unsigned long long* __restrict__ plist64,
                                  const unsigned* __restrict__ cnt, const float* __restrict__ bc,
                                  float* __restrict__ out_pooled) {
  const int j = blockIdx.x * 256 + threadIdx.x;
  if (j >= N_PTS) return;
  const unsigned r = unq_inv[j];
  plist64[atomicAdd(&cur[r], 1u)] = ((unsigned long long)r << 32) | (unsigned)j;
  if (cnt[j] == 0) {
    #pragma unroll
    for (int c = 0; c < 16; ++c) out_pooled[(size_t)j * 16 + c] = fmaxf(bc[c], 0.f);
  }
}

// ---- block-wide GEMM stage, column-strip waves, SWAPPED-D epilogue (b64 LDS writes) ----
// mfma(w_frag, x_frag): D row'=quad*4+r = OUT COLUMN, D col=l15 = OUT ROW (within mt tile).
// Weight frags double-buffered (kc+1 prefetched during kc's MFMA chain) to keep global
// loads in flight — VGPR budget 128 @ 4 waves/EU, acc uses 64, prefetch uses the rest.
template<int K, int C, bool RELU, bool MIDB>
__device__ __forceinline__ void gemm_stage(
    const unsigned short* __restrict__ Wt,     // [C][K] bf16, global (L2-hot)
    const float* __restrict__ bias,            // [C]
    const unsigned short* in,                  // LDS, pitch PA (col-offset base)
    unsigned short* outp,                      // LDS, pitch PA (may overlap in)
    int wave, int l15, int quad)
{
  constexpr int KC = K / 32;
  constexpr int NT = C / 64;                   // 16-col tiles per wave (weights read ONCE/block)
  f32x4 acc[4][NT];
  #pragma unroll
  for (int mt = 0; mt < 4; ++mt)
    #pragma unroll
    for (int nt = 0; nt < NT; ++nt) acc[mt][nt] = (f32x4){0.f, 0.f, 0.f, 0.f};
  const unsigned short* wp[NT];
  #pragma unroll
  for (int nt = 0; nt < NT; ++nt)
    wp[nt] = Wt + (size_t)(wave * 16 * NT + nt * 16 + l15) * K + quad * 8;
  bf16x8 bcur[NT], bnxt[NT];
  #pragma unroll
  for (int nt = 0; nt < NT; ++nt)
    bcur[nt] = __builtin_bit_cast(bf16x8, *(const short8*)(wp[nt]));
  #pragma unroll
  for (int kc = 0; kc < KC; ++kc) {
    if (kc + 1 < KC) {
      #pragma unroll
      for (int nt = 0; nt < NT; ++nt)
        bnxt[nt] = __builtin_bit_cast(bf16x8, *(const short8*)(wp[nt] + (kc + 1) * 32));
    }
    #pragma unroll
    for (int mt = 0; mt < 4; ++mt) {
      bf16x8 a = __builtin_bit_cast(bf16x8, *(const short8*)&in[(mt * 16 + l15) * PA + kc * 32 + quad * 8]);
      #pragma unroll
      for (int nt = 0; nt < NT; ++nt)
        acc[mt][nt] = __builtin_amdgcn_mfma_f32_16x16x32_bf16(bcur[nt], a, acc[mt][nt], 0, 0, 0);
    }
    #pragma unroll
    for (int nt = 0; nt < NT; ++nt) bcur[nt] = bnxt[nt];
  }
  if (MIDB) __syncthreads();                   // reads drained before overlapping writes
  #pragma unroll
  for (int mt = 0; mt < 4; ++mt)
    #pragma unroll
    for (int nt = 0; nt < NT; ++nt) {
      const int cbase = wave * 16 * NT + nt * 16 + quad * 4;
      const f32x4 bs = *(const f32x4*)&bias[cbase];
      unsigned short h[4];
      #pragma unroll
      for (int r = 0; r < 4; ++r) {
        float y = acc[mt][nt][r] + bs[r];
        if (RELU) y = fmaxf(y, 0.f);
        h[r] = f2bf(y);
      }
      uint2 pk; pk.x = (unsigned)h[0] | ((unsigned)h[1] << 16);
      pk.y = (unsigned)h[2] | ((unsigned)h[3] << 16);
      *(uint2*)&outp[(mt * 16 + l15) * PA + cbase] = pk;   // ds_write_b64
    }
  __syncthreads();
}

// ---------------- fused MLP + sparse segment-max fixup + compression + labels ----
__global__ __launch_bounds__(256, 4) void mlp_pool_kernel(
    const float* __restrict__ ptfea, const float* __restrict__ xyz, const int* __restrict__ shuf,
    const unsigned long long* __restrict__ plist64,
    const unsigned* __restrict__ offv, const unsigned* __restrict__ cnt,
    const int* __restrict__ ptlab, const unsigned* __restrict__ unqvals,
    const float* __restrict__ s0, const float* __restrict__ t0,
    const float* __restrict__ w1e, const float* __restrict__ be1,
    const unsigned short* __restrict__ w2t, const float* __restrict__ be2,
    const unsigned short* __restrict__ w3t, const float* __restrict__ be3,
    const unsigned short* __restrict__ w4t, const float* __restrict__ b4,
    const unsigned short* __restrict__ wct, const float* __restrict__ bc,
    unsigned short* __restrict__ partials, float* __restrict__ out_pooled,
    float* __restrict__ out_lab)
{
  __shared__ __align__(16) unsigned short buf[64 * PA];
  __shared__ int segs[64];
  __shared__ int jrows[64];
  __shared__ int s_alast;
  __shared__ int s_nrun;
  __shared__ unsigned short s_runs[32];              // (r<<8)|e for runs with len>1
  __shared__ unsigned char s_lead[64], s_comp[64];
  const int tid  = threadIdx.x;
  const int wave = tid >> 6, lane = tid & 63;
  const int l15 = lane & 15, quad = lane >> 4;
  const int row0 = blockIdx.x * 64;

  if (tid == 0) { s_alast = 0; s_nrun = 0; }
  if (lane < 16) {                                   // wave-local write; same-wave read below
    const int r = wave * 16 + lane;
    const unsigned long long v = plist64[row0 + r];
    jrows[r] = (int)(unsigned)v;
    segs[r]  = (int)(unsigned)(v >> 32);
  }

  // ---- stage 0: features + bn0 + layer1 (scalar fp32); 4 lanes/row, wave-local rows ----
  {
    const int r = wave * 16 + (lane >> 2), part = lane & 3;
    const int sj = shuf[jrows[r]];
    const float PI_F = 3.14159265358979323846f;
    const float minb[3] = {0.0f, -PI_F, -4.0f};
    const float maxb[3] = {50.0f, PI_F, 2.0f};
    const float gm1[3]  = {479.0f, 359.0f, 31.0f};
    float x0[9];
    #pragma unroll
    for (int d = 0; d < 3; ++d) {
      float itv = (maxb[d] - minb[d]) / gm1[d];
      float x   = xyz[(size_t)sj * 3 + d];
      float cl  = fminf(fmaxf(x, minb[d]), maxb[d]);
      float fi  = floorf((cl - minb[d]) / itv);
      float center = (fi + 0.5f) * itv + minb[d];
      x0[d] = (x - center) * s0[d] + t0[d];           // bn0 folded
    }
    #pragma unroll
    for (int d = 0; d < 6; ++d) x0[3 + d] = ptfea[(size_t)sj * 6 + d] * s0[3 + d] + t0[3 + d];
    unsigned short h[16];
    #pragma unroll
    for (int ci = 0; ci < 16; ++ci) {
      float acc = be1[part * 16 + ci];
      #pragma unroll
      for (int k = 0; k < 9; ++k) acc += x0[k] * w1e[k * 64 + part * 16 + ci];
      h[ci] = f2bf(fmaxf(acc, 0.0f));
    }
    *(short8*)&buf[r * PA + part * 16]     = *(short8*)&h[0];
    *(short8*)&buf[r * PA + part * 16 + 8] = *(short8*)&h[8];
  }
  __syncthreads();                                   // B1: h1 + segs/jrows visible

  // ---- wave 0: run analysis + labels for complete runs (overlaps waves 1-3's L2 stage;
  //      s_* consumed only after L4, several barriers later) ----
  if (tid < 64) {
    const int r = tid;
    bool lead = (r == 0) || (segs[r] != segs[r - 1]);
    s_lead[r] = lead ? 1 : 0;
    unsigned char comp = 0;
    int e = r + 1;
    if (lead) {
      atomicMax(&s_alast, r);
      while (e < 64 && segs[e] == segs[r]) ++e;
      const unsigned s = (unsigned)segs[r];
      comp = (offv[s] == (unsigned)(row0 + r) && offv[s] + cnt[s] == (unsigned)(row0 + e)) ? 1 : 0;
    }
    s_comp[r] = comp;
    if (comp) {                                      // label argmax: first max = smallest label
      int bestl;
      if (e - r == 1) bestl = ptlab[jrows[r]];
      else {
        int bestc = 0; bestl = 32;
        for (int i = r; i < e; ++i) {
          const int li = ptlab[jrows[i]];
          int cc = 0;
          for (int k2 = r; k2 < e; ++k2) cc += (ptlab[jrows[k2]] == li) ? 1 : 0;
          if (cc > bestc || (cc == bestc && li < bestl)) { bestc = cc; bestl = li; }
        }
      }
      out_lab[unqvals[segs[r]]] = (float)bestl;
    }
    const bool multi = lead && (e - r) > 1;
    unsigned long long mm = __ballot(multi);
    if (multi) {
      int idx = (int)__popcll(mm & ((1ull << r) - 1ull));
      s_runs[idx] = (unsigned short)((r << 8) | e);
    }
    if (tid == 0) s_nrun = (int)__popcll(mm);
  }

  // ---- L2 [64->128] cols 0->136 (disjoint: no mid barrier); L3 [128->256] 136->0; L4 in-place ----
  gemm_stage< 64, 128, true,  false>(w2t, be2, buf,       buf + 136, wave, l15, quad);
  gemm_stage<128, 256, true,  true >(w3t, be3, buf + 136, buf,       wave, l15, quad);
  gemm_stage<256, 256, false, true >(w4t, b4,  buf,       buf,       wave, l15, quad);

  // ---- sparse fixup: per multi-run, column-thread computes run max into the leader row ----
  {
    const int n = s_nrun;
    for (int i = 0; i < n; ++i) {
      const int re = s_runs[i];
      const int r = re >> 8, e = re & 255;
      float m = bf2f(buf[r * PA + tid]);
      for (int rr = r + 1; rr < e; ++rr) m = fmaxf(m, bf2f(buf[rr * PA + tid]));
      buf[r * PA + tid] = f2bf(m);
    }
  }
  __syncthreads();

  // ---- boundary partials (first/last incomplete runs; rows 0 and alast are leaders) ----
  {
    const int c = tid;
    const int alast = s_alast;
    const size_t b2 = (size_t)blockIdx.x * 2;
    if (!s_comp[0])     partials[b2 * 256 + c]       = buf[0 * PA + c];
    if (!s_comp[alast]) partials[(b2 + 1) * 256 + c] = buf[alast * PA + c];
  }

  // ---- compression: pooled[rows wave*16+l15, 256] @ wct^T; swapped-D -> float4 stores ----
  {
    const unsigned short* wp = wct + l15 * 256 + quad * 8;
    bf16x8 wv[8];
    #pragma unroll
    for (int kc = 0; kc < 8; ++kc)
      wv[kc] = __builtin_bit_cast(bf16x8, *(const short8*)(wp + kc * 32));
    f32x4 acc = (f32x4){0.f, 0.f, 0.f, 0.f};
    #pragma unroll
    for (int kc = 0; kc < 8; ++kc) {
      bf16x8 x = __builtin_bit_cast(bf16x8, *(const short8*)&buf[(wave * 16 + l15) * PA + kc * 32 + quad * 8]);
      acc = __builtin_amdgcn_mfma_f32_16x16x32_bf16(wv[kc], x, acc, 0, 0, 0);
    }
    const int r1 = wave * 16 + l15;                  // pooled row (D col = l15)
    if (s_lead[r1] && s_comp[r1]) {
      const f32x4 bcv = *(const f32x4*)&bc[quad * 4];
      f32x4 v;
      #pragma unroll
      for (int r = 0; r < 4; ++r) v[r] = fmaxf(acc[r] + bcv[r], 0.f);   // cols quad*4+r
      *(f32x4*)&out_pooled[(size_t)segs[r1] * 16 + quad * 4] = v;
    }
  }
}

// ---------------- merge block-spanning segments from partials (+ their labels) ----
__global__ __launch_bounds__(256) void merge_kernel(
    const unsigned long long* __restrict__ plist64,
    const unsigned* __restrict__ offv, const unsigned* __restrict__ cnt,
    const unsigned short* __restrict__ partials,
    const int* __restrict__ ptlab, const unsigned* __restrict__ unqvals,
    const float* __restrict__ wc, const float* __restrict__ bc,
    float* __restrict__ out_pooled, float* __restrict__ out_lab)
{
  __shared__ float pooled[256];
  __shared__ float psum[256];
  const int b = blockIdx.x;
  const unsigned s = (unsigned)(plist64[(size_t)b * 64 + 63] >> 32);
  const unsigned o = offv[s], e = o + cnt[s];
  if ((o >> 6) != (unsigned)b) return;              // owner = block where segment starts
  if (e <= (unsigned)(b + 1) * 64) return;          // doesn't span a boundary
  const int B1 = (int)((e - 1) >> 6);
  const int c = threadIdx.x;
  float m = bf2f(partials[((size_t)2 * b + 1) * 256 + c]);    // head partial (last run of b)
  for (int bb = b + 1; bb <= B1; ++bb)
    m = fmaxf(m, bf2f(partials[(size_t)2 * bb * 256 + c]));   // tails (first run of bb)
  pooled[c] = m;
  __syncthreads();
  const int co = c & 15, kg = c >> 4;
  float p = 0.f;
  #pragma unroll
  for (int k = kg * 16; k < kg * 16 + 16; ++k) p += pooled[k] * wc[k * 16 + co];
  psum[c] = p;
  __syncthreads();
  if (c < 16) {
    float acc = bc[c];
    #pragma unroll
    for (int g = 0; g < 16; ++g) acc += psum[g * 16 + c];
    out_pooled[(size_t)s * 16 + c] = fmaxf(acc, 0.f);
  }
  if (c == 0) {                                     // label argmax over the spanning segment
    int bestc = 0, bestl = 32;
    for (unsigned i = o; i < e; ++i) {
      const int li = ptlab[(unsigned)plist64[i]];
      int cc = 0;
      for (unsigned k2 = o; k2 < e; ++k2) cc += (ptlab[(unsigned)plist64[k2]] == li) ? 1 : 0;
      if (cc > bestc || (cc == bestc && li < bestl)) { bestc = cc; bestl = li; }
    }
    out_lab[unqvals[s]] = (float)bestl;
  }
}

extern "C" void kernel_launch(void* const* d_in, const int* in_sizes, int n_in,
                              void* d_out, int out_size, void* d_ws, size_t ws_size,
                              hipStream_t stream)
{
  const float* pt_fea = (const float*)d_in[0];
  const float* xyz    = (const float*)d_in[1];
  const int*   bidx   = (const int*)d_in[2];
  const int*   ptlab  = (const int*)d_in[3];
  const int*   shuf   = (const int*)d_in[4];
  const float* bng0 = (const float*)d_in[5],  *bnb0 = (const float*)d_in[6],  *bnm0 = (const float*)d_in[7],  *bnv0 = (const float*)d_in[8];
  const float* bng1 = (const float*)d_in[9],  *bnb1 = (const float*)d_in[10], *bnm1 = (const float*)d_in[11], *bnv1 = (const float*)d_in[12];
  const float* bng2 = (const float*)d_in[13], *bnb2 = (const float*)d_in[14], *bnm2 = (const float*)d_in[15], *bnv2 = (const float*)d_in[16];
  const float* bng3 = (const float*)d_in[17], *bnb3 = (const float*)d_in[18], *bnm3 = (const float*)d_in[19], *bnv3 = (const float*)d_in[20];
  const float* w1 = (const float*)d_in[21], *b1 = (const float*)d_in[22];
  const float* w2 = (const float*)d_in[23], *b2 = (const float*)d_in[24];
  const float* w3 = (const float*)d_in[25], *b3 = (const float*)d_in[26];
  const float* w4 = (const float*)d_in[27], *b4 = (const float*)d_in[28];
  const float* wc = (const float*)d_in[29], *bc = (const float*)d_in[30];

  float* out        = (float*)d_out;                // outputs int64/f32/int32 -> float32 buffer
  float* out_unq    = out;                          // [240000]
  float* out_pooled = out + 240000;                 // [240000,16]
  float* out_lab    = out + 4080000;                // [2,480,360,32]
  float* out_cat    = out + 15139200;               // [240000,4]

  char* wsb = (char*)d_ws;
  size_t o = 0;
  auto alloc = [&](size_t bytes) -> void* { void* p = wsb + o; o = (o + bytes + 255) & ~(size_t)255; return p; };
  // zero-init region (single memset): bitmap | cnt
  unsigned long long* bitmap = (unsigned long long*)alloc((size_t)NWORDS * 8);
  unsigned* cnt    = (unsigned*)alloc((size_t)N_PTS * 4);
  const size_t zero_bytes = o;
  float* s0  = (float*)alloc(9 * 4);
  float* t0  = (float*)alloc(9 * 4);
  float* w1e = (float*)alloc(576 * 4);
  float* be1 = (float*)alloc(64 * 4);
  float* be2 = (float*)alloc(128 * 4);
  float* be3 = (float*)alloc(256 * 4);
  unsigned short* w2t = (unsigned short*)alloc(8192 * 2);
  unsigned short* w3t = (unsigned short*)alloc(32768 * 2);
  unsigned short* w4t = (unsigned short*)alloc(65536 * 2);
  unsigned short* wct = (unsigned short*)alloc(4096 * 2);
  unsigned* flatkeys = (unsigned*)alloc((size_t)N_PTS * 4);
  unsigned* unq_inv  = (unsigned*)alloc((size_t)N_PTS * 4);
  unsigned* unqvals  = (unsigned*)alloc((size_t)N_PTS * 4);
  unsigned* offv     = (unsigned*)alloc((size_t)N_PTS * 4);
  unsigned* cur      = (unsigned*)alloc((size_t)N_PTS * 4);
  unsigned long long* plist64 = (unsigned long long*)alloc((size_t)N_PTS * 8);
  unsigned* wordpref = (unsigned*)alloc((size_t)NWORDS * 4);
  unsigned* bsumA    = (unsigned*)alloc(NB_WORD * 4);
  unsigned* bsumB    = (unsigned*)alloc(NB_PT * 4);
  unsigned short* partials = (unsigned short*)alloc((size_t)NBLK_MLP * 2 * 256 * 2);
  // total ~14 MB

  hipMemsetAsync(bitmap, 0, zero_bytes, stream);
  hipMemsetAsync(out_lab, 0, (size_t)NV * 4, stream);       // float 0.0f == all-zero bytes

  prep_vox_kernel<<<256 + NB_PT, 256, 0, stream>>>(
      bng0, bnb0, bnm0, bnv0, bng1, bnb1, bnm1, bnv1,
      bng2, bnb2, bnm2, bnv2, bng3, bnb3, bnm3, bnv3,
      w1, b1, w2, b2, w3, b3, w4, wc,
      s0, t0, w1e, be1, be2, be3, w2t, w3t, w4t, wct,
      xyz, bidx, flatkeys, bitmap, out_cat, out_unq);
  reduce_words<<<NB_WORD, 256, 0, stream>>>(bitmap, bsumA);
  scatter_unq<<<NB_WORD, 256, 0, stream>>>(bitmap, bsumA, wordpref, unqvals, out_unq);
  inv_kernel<<<NB_PT, 256, 0, stream>>>(flatkeys, bitmap, wordpref, unq_inv, cnt);
  reduce_cnt<<<NB_PT, 256, 0, stream>>>(cnt, bsumB);
  scan_cnt<<<NB_PT, 256, 0, stream>>>(cnt, bsumB, offv, cur);
  plist_fill_kernel<<<NB_PT, 256, 0, stream>>>(unq_inv, cur, plist64, cnt, bc, out_pooled);
  mlp_pool_kernel<<<NBLK_MLP, 256, 0, stream>>>(pt_fea, xyz, shuf, plist64, offv, cnt,
                                                ptlab, unqvals,
                                                s0, t0, w1e, be1, w2t, be2, w3t, be3, w4t, b4,
                                                wct, bc, partials, out_pooled, out_lab);
  merge_kernel<<<NBLK_MLP, 256, 0, stream>>>(plist64, offv, cnt, partials,
                                             ptlab, unqvals, wc, bc, out_pooled, out_lab);
}